// Round 8
// baseline (2512.765 us; speedup 1.0000x reference)
//
#include <hip/hip_runtime.h>
#include <hip/hip_bf16.h>
#include <math.h>

// Problem constants (MambaStack reference)
#define DEPTH   2
#define DM      768      // d_model
#define DS      64       // d_state
#define DC      4        // d_conv
#define DI      1536     // d_inner
#define DTR     48       // dt_rank
#define BATCH   4
#define SEQ     2048
#define MROWS   (BATCH*SEQ)          // 8192
#define XDC     (DTR + 2*DS)         // 176 (xdbl cols)
#define NC      8                    // scan chunks
#define TCH     (SEQ/NC)             // 256 timesteps per chunk
#define LOG2E   1.44269504088896f

typedef __attribute__((ext_vector_type(8))) short bf16x8;
typedef __attribute__((ext_vector_type(4))) float f32x4;
typedef unsigned short ushort_t;
#define GAS __attribute__((address_space(1)))
#define LAS __attribute__((address_space(3)))

__device__ __forceinline__ float silu_fast(float x) {
    return x / (1.f + __expf(-x));
}
__device__ __forceinline__ float softplus_acc(float x) {
    return x > 20.f ? x : log1pf(expf(x));
}

// Split fp32 -> (hi, lo) bf16 pair, both RNE.  hi+lo represents f to ~2^-17.
__device__ __forceinline__ void bf16_split(float f, ushort_t& h, ushort_t& l) {
    unsigned u = __float_as_uint(f);
    unsigned hr = u + 0x7FFF + ((u >> 16) & 1);
    h = (ushort_t)(hr >> 16);
    float lof = f - __uint_as_float((unsigned)h << 16);
    unsigned ul = __float_as_uint(lof);
    unsigned lr = ul + 0x7FFF + ((ul >> 16) & 1);
    l = (ushort_t)(lr >> 16);
}

// Contiguous fp32 array -> hi/lo bf16 planes.  n multiple of 1024.
__global__ __launch_bounds__(256) void split_bf16(
    const float* __restrict__ in, ushort_t* __restrict__ hi,
    ushort_t* __restrict__ lo)
{
    const size_t i = ((size_t)blockIdx.x * 256 + threadIdx.x) * 4;
    const float4 v = *(const float4*)(in + i);
    ushort4 h, l;
    bf16_split(v.x, h.x, l.x); bf16_split(v.y, h.y, l.y);
    bf16_split(v.z, h.z, l.z); bf16_split(v.w, h.w, l.w);
    *(ushort4*)(hi + i) = h;
    *(ushort4*)(lo + i) = l;
}

// ---------------- bf16x2-split MFMA GEMM ----------------
// C[M,N] = (Ah+Al) @ (Wh+Wl)^T, planes bf16, row strides ldA/ldW (elements).
// 128x128 tile, BK=32, 4 waves; 16x16x32 MFMA, 3 per tile (hh, hl, lh).
__global__ __launch_bounds__(256, 2) void gemm_mfma(
    const ushort_t* __restrict__ Ah, const ushort_t* __restrict__ Al,
    const ushort_t* __restrict__ Wh, const ushort_t* __restrict__ Wl,
    float* __restrict__ C, int N, int K, int ldA, int ldW)
{
    __shared__ ushort_t lds[4][128 * 32];
    const int tid  = threadIdx.x;
    const int wave = tid >> 6, lane = tid & 63;
    const int bm0 = blockIdx.y * 128, bn0 = blockIdx.x * 128;
    const int wm = (wave >> 1) * 64, wn = (wave & 1) * 64;

    const ushort_t* gp = (wave == 0) ? Ah : (wave == 1) ? Al : (wave == 2) ? Wh : Wl;
    const int ldg = (wave < 2) ? ldA : ldW;
    const int rb = (wave < 2) ? bm0 : bn0;
    const int srow = lane >> 2;           // 0..15
    const int skq  = (lane & 3) * 8;      // k offset in elements

    f32x4 acc[4][4];
#pragma unroll
    for (int i = 0; i < 4; i++)
#pragma unroll
        for (int j = 0; j < 4; j++) acc[i][j] = (f32x4){0.f, 0.f, 0.f, 0.f};

    const int lm  = lane & 15;
    const int kg8 = (lane >> 4) * 8;

    for (int k0 = 0; k0 < K; k0 += 32) {
#pragma unroll
        for (int j = 0; j < 8; j++) {
            const ushort_t* ga = gp + (size_t)(rb + j * 16 + srow) * ldg + k0 + skq;
            __builtin_amdgcn_global_load_lds(
                (const GAS unsigned*)ga, (LAS unsigned*)&lds[wave][j * 512], 16, 0, 0);
        }
        __syncthreads();

        bf16x8 ah[4], al[4], bh[4], bl[4];
#pragma unroll
        for (int i = 0; i < 4; i++) {
            const int ar = (wm + i * 16 + lm) * 32 + kg8;
            ah[i] = *(const bf16x8*)&lds[0][ar];
            al[i] = *(const bf16x8*)&lds[1][ar];
            const int br = (wn + i * 16 + lm) * 32 + kg8;
            bh[i] = *(const bf16x8*)&lds[2][br];
            bl[i] = *(const bf16x8*)&lds[3][br];
        }
#pragma unroll
        for (int mi = 0; mi < 4; mi++)
#pragma unroll
            for (int ni = 0; ni < 4; ni++) {
                f32x4 t = acc[mi][ni];
                t = __builtin_amdgcn_mfma_f32_16x16x32_bf16(al[mi], bh[ni], t, 0, 0, 0);
                t = __builtin_amdgcn_mfma_f32_16x16x32_bf16(ah[mi], bl[ni], t, 0, 0, 0);
                t = __builtin_amdgcn_mfma_f32_16x16x32_bf16(ah[mi], bh[ni], t, 0, 0, 0);
                acc[mi][ni] = t;
            }
        __syncthreads();
    }

#pragma unroll
    for (int mi = 0; mi < 4; mi++)
#pragma unroll
        for (int ni = 0; ni < 4; ni++)
#pragma unroll
            for (int r = 0; r < 4; r++) {
                const int rowg = bm0 + wm + mi * 16 + (lane >> 4) * 4 + r;
                const int colg = bn0 + wn + ni * 16 + lm;
                C[(size_t)rowg * N + colg] = acc[mi][ni][r];
            }
}

// C[M,N] = A @ W^T where A is given K-MAJOR per batch: AT[(b*K + k)*SEQ + t].
__global__ __launch_bounds__(256, 2) void gemm_tn(
    const float* __restrict__ AT,
    const float* __restrict__ W,
    float* __restrict__ C, int ldC,
    int N, int K)
{
    __shared__ float As[8][132];
    __shared__ float Bs[8][132];
    const int tid = threadIdx.x;
    const int bm0 = blockIdx.y * 128;
    const int bn0 = blockIdx.x * 128;
    const int bb  = bm0 / SEQ;
    const int t0  = bm0 - bb * SEQ;
    const int tx = tid & 15;
    const int ty = tid >> 4;
    const int arow = tid >> 5;
    const int am4  = (tid & 31) * 4;
    const int lrow = tid >> 1;
    const int lk4  = (tid & 1) * 4;

    float acc[8][8];
#pragma unroll
    for (int i = 0; i < 8; i++)
#pragma unroll
        for (int j = 0; j < 8; j++) acc[i][j] = 0.f;

    for (int k0 = 0; k0 < K; k0 += 8) {
        const float4 av = *(const float4*)(AT + ((size_t)(bb * K + k0 + arow)) * SEQ + t0 + am4);
        float4 wv;
        const int wrow = bn0 + lrow;
        if (wrow < N) wv = *(const float4*)(W + (size_t)wrow * K + (k0 + lk4));
        else          wv = make_float4(0.f, 0.f, 0.f, 0.f);
        __syncthreads();
        *(float4*)&As[arow][am4] = av;
        Bs[lk4 + 0][lrow] = wv.x; Bs[lk4 + 1][lrow] = wv.y;
        Bs[lk4 + 2][lrow] = wv.z; Bs[lk4 + 3][lrow] = wv.w;
        __syncthreads();
#pragma unroll
        for (int kk = 0; kk < 8; kk++) {
            const float4 a0 = *(const float4*)&As[kk][ty * 8];
            const float4 a1 = *(const float4*)&As[kk][ty * 8 + 4];
            const float4 b0 = *(const float4*)&Bs[kk][tx * 8];
            const float4 b1 = *(const float4*)&Bs[kk][tx * 8 + 4];
            const float ar[8] = {a0.x, a0.y, a0.z, a0.w, a1.x, a1.y, a1.z, a1.w};
            const float br[8] = {b0.x, b0.y, b0.z, b0.w, b1.x, b1.y, b1.z, b1.w};
#pragma unroll
            for (int i = 0; i < 8; i++)
#pragma unroll
                for (int j = 0; j < 8; j++)
                    acc[i][j] = fmaf(ar[i], br[j], acc[i][j]);
        }
    }

#pragma unroll
    for (int i = 0; i < 8; i++) {
        const int row = bm0 + ty * 8 + i;
#pragma unroll
        for (int j4 = 0; j4 < 8; j4 += 4) {
            const int col = bn0 + tx * 8 + j4;
            if (col + 3 < N) {
                *(float4*)(C + (size_t)row * ldC + col) =
                    make_float4(acc[i][j4], acc[i][j4 + 1], acc[i][j4 + 2], acc[i][j4 + 3]);
            }
        }
    }
}

// dt GEMM (small K=48): C = softplus(A[:, :48] @ W^T + bias), row-major.
__global__ __launch_bounds__(256, 2) void gemm_dt(
    const float* __restrict__ A, int ldA,
    const float* __restrict__ W,
    const float* __restrict__ bias,
    float* __restrict__ C, int ldC,
    int N, int K)
{
    __shared__ float As[8][132];
    __shared__ float Bs[8][132];
    const int tid = threadIdx.x;
    const int bm0 = blockIdx.y * 128;
    const int bn0 = blockIdx.x * 128;
    const int tx = tid & 15;
    const int ty = tid >> 4;
    const int lrow = tid >> 1;
    const int lk4  = (tid & 1) * 4;

    float acc[8][8];
#pragma unroll
    for (int i = 0; i < 8; i++)
#pragma unroll
        for (int j = 0; j < 8; j++) acc[i][j] = 0.f;

    for (int k0 = 0; k0 < K; k0 += 8) {
        const float4 av = *(const float4*)(A + (size_t)(bm0 + lrow) * ldA + (k0 + lk4));
        float4 wv;
        const int wrow = bn0 + lrow;
        if (wrow < N) wv = *(const float4*)(W + (size_t)wrow * K + (k0 + lk4));
        else          wv = make_float4(0.f, 0.f, 0.f, 0.f);
        __syncthreads();
        As[lk4 + 0][lrow] = av.x; As[lk4 + 1][lrow] = av.y;
        As[lk4 + 2][lrow] = av.z; As[lk4 + 3][lrow] = av.w;
        Bs[lk4 + 0][lrow] = wv.x; Bs[lk4 + 1][lrow] = wv.y;
        Bs[lk4 + 2][lrow] = wv.z; Bs[lk4 + 3][lrow] = wv.w;
        __syncthreads();
#pragma unroll
        for (int kk = 0; kk < 8; kk++) {
            const float4 a0 = *(const float4*)&As[kk][ty * 8];
            const float4 a1 = *(const float4*)&As[kk][ty * 8 + 4];
            const float4 b0 = *(const float4*)&Bs[kk][tx * 8];
            const float4 b1 = *(const float4*)&Bs[kk][tx * 8 + 4];
            const float ar[8] = {a0.x, a0.y, a0.z, a0.w, a1.x, a1.y, a1.z, a1.w};
            const float br[8] = {b0.x, b0.y, b0.z, b0.w, b1.x, b1.y, b1.z, b1.w};
#pragma unroll
            for (int i = 0; i < 8; i++)
#pragma unroll
                for (int j = 0; j < 8; j++)
                    acc[i][j] = fmaf(ar[i], br[j], acc[i][j]);
        }
    }

#pragma unroll
    for (int i = 0; i < 8; i++) {
        const int row = bm0 + ty * 8 + i;
#pragma unroll
        for (int j4 = 0; j4 < 8; j4 += 4) {
            const int col = bn0 + tx * 8 + j4;
            if (col + 3 < N) {
                float4 v = make_float4(acc[i][j4], acc[i][j4 + 1], acc[i][j4 + 2], acc[i][j4 + 3]);
                v.x = softplus_acc(v.x + bias[col + 0]);
                v.y = softplus_acc(v.y + bias[col + 1]);
                v.z = softplus_acc(v.z + bias[col + 2]);
                v.w = softplus_acc(v.w + bias[col + 3]);
                *(float4*)(C + (size_t)row * ldC + col) = v;
            }
        }
    }
}

// Depthwise causal conv (K=4) + SiLU -> uT [b][d][t] only.
__global__ __launch_bounds__(256) void conv_silu_T(
    const float* __restrict__ xz, const float* __restrict__ cw,
    const float* __restrict__ cb, float* __restrict__ uT)
{
    __shared__ float tin[67][65];
    __shared__ float ttr[64][65];
    const int tid = threadIdx.x;
    const int d0 = blockIdx.x * 64, t0 = blockIdx.y * 64, b = blockIdx.z;
    const int cl = tid & 63, q = tid >> 6;

    for (int r = q; r < 67; r += 4) {
        const int t = t0 - 3 + r;
        float v = 0.f;
        if (t >= 0) v = xz[((size_t)b * SEQ + t) * (2 * DI) + d0 + cl];
        tin[r][cl] = v;
    }
    __syncthreads();

    const float4 w = ((const float4*)cw)[d0 + cl];
    const float bb = cb[d0 + cl];
#pragma unroll
    for (int i = 0; i < 16; i++) {
        const int t = q * 16 + i;
        float a = bb;
        a = fmaf(tin[t + 0][cl], w.x, a);
        a = fmaf(tin[t + 1][cl], w.y, a);
        a = fmaf(tin[t + 2][cl], w.z, a);
        a = fmaf(tin[t + 3][cl], w.w, a);
        ttr[cl][t] = silu_fast(a);
    }
    __syncthreads();
#pragma unroll
    for (int i = 0; i < 16; i++) {
        const int d = q * 16 + i;
        uT[((size_t)b * DI + d0 + d) * SEQ + t0 + cl] = ttr[d][cl];
    }
}

// Tiled transpose: in[row=b*SEQ+t, coloff+c] (ld ldin) -> out[(b*ncols+c)*SEQ + t]
__global__ __launch_bounds__(256) void trans_r2t(
    const float* __restrict__ in, int ldin, int coloff,
    float* __restrict__ out, int ncols)
{
    __shared__ float tile[64][65];
    const int tid = threadIdx.x;
    const int c0 = blockIdx.x * 64, t0 = blockIdx.y * 64, b = blockIdx.z;
    const int cl = tid & 63, q = tid >> 6;
#pragma unroll
    for (int i = 0; i < 16; i++) {
        const int r = q * 16 + i;
        tile[r][cl] = in[((size_t)b * SEQ + t0 + r) * ldin + coloff + c0 + cl];
    }
    __syncthreads();
#pragma unroll
    for (int i = 0; i < 16; i++) {
        const int cc = q * 16 + i;
        out[((size_t)b * ncols + c0 + cc) * SEQ + t0 + cl] = tile[cl][cc];
    }
}

// Fused dt transpose + du=dt*u producer (sep mode).
__global__ __launch_bounds__(256) void dtdu_T(
    const float* __restrict__ xz, const float* __restrict__ uT,
    float* __restrict__ dtT, float* __restrict__ duT)
{
    __shared__ float tile[64][65];
    const int tid = threadIdx.x;
    const int d0 = blockIdx.x * 64, t0 = blockIdx.y * 64, b = blockIdx.z;
    const int cl = tid & 63, q = tid >> 6;
#pragma unroll
    for (int i = 0; i < 16; i++) {
        const int r = q * 16 + i;
        tile[r][cl] = xz[((size_t)b * SEQ + t0 + r) * (2 * DI) + d0 + cl];
    }
    __syncthreads();
#pragma unroll
    for (int i = 0; i < 16; i++) {
        const int dd = q * 16 + i;
        const size_t off = ((size_t)b * DI + d0 + dd) * SEQ + t0 + cl;
        const float dtv = tile[cl][dd];
        dtT[off] = dtv;
        duT[off] = dtv * uT[off];
    }
}

// B/C transpose into lane-interleaved layout:
//   bc4[(b*(SEQ/4) + t/4)*128 + ch] = float4{ x[t..t+3][ch] }
__global__ __launch_bounds__(256) void trans_bc_i4(
    const float* __restrict__ in, float4* __restrict__ bc4)
{
    __shared__ float tile[64][65];
    const int tid = threadIdx.x;
    const int c0 = blockIdx.x * 64, t0 = blockIdx.y * 64, b = blockIdx.z;
    const int cl = tid & 63, q = tid >> 6;
#pragma unroll
    for (int i = 0; i < 16; i++) {
        const int r = q * 16 + i;
        tile[r][cl] = in[((size_t)b * SEQ + t0 + r) * XDC + DTR + c0 + cl];
    }
    __syncthreads();
#pragma unroll
    for (int i = 0; i < 4; i++) {
        const int j = q * 4 + i;
        const float4 v = make_float4(tile[4 * j + 0][cl], tile[4 * j + 1][cl],
                                     tile[4 * j + 2][cl], tile[4 * j + 3][cl]);
        bc4[((size_t)b * (SEQ / 4) + (t0 / 4 + j)) * 128 + c0 + cl] = v;
    }
}

// ---------------- Chunked selective scan ----------------

// Fallback (in-place) phase1: dt/u streams.
__global__ __launch_bounds__(256, 4) void scan_phase1(
    const float* __restrict__ dtT, const float* __restrict__ uT,
    const float4* __restrict__ bc4, const float* __restrict__ A_log,
    float* __restrict__ hend, float* __restrict__ prodA)
{
    const int wid  = __builtin_amdgcn_readfirstlane(
                        (int)((blockIdx.x * 256 + threadIdx.x) >> 6));
    const int lane = threadIdx.x & 63;
    const int c  = wid & (NC - 1);
    const int bd = wid >> 3;
    const int b  = bd / DI;
    const int d  = bd - b * DI;

    const float An = -expf(A_log[d * DS + lane]) * LOG2E;
    const float* dtp = dtT + (size_t)bd * SEQ + c * TCH;
    const float* up  = uT  + (size_t)bd * SEQ + c * TCH;
    const float4* Bp = bc4 + ((size_t)b * (SEQ / 4) + c * (TCH / 4)) * 128 + lane;

    float h = 0.f, sdt = 0.f;
    for (int tb = 0; tb < TCH; tb += 16) {
#pragma unroll
        for (int g = 0; g < 4; g++) {
            const float4 B4  = Bp[(size_t)(tb / 4 + g) * 128];
            const float4 dt4 = *(const float4*)(dtp + tb + 4 * g);
            const float4 u4  = *(const float4*)(up  + tb + 4 * g);
            h = fmaf(exp2f(dt4.x * An), h, (dt4.x * u4.x) * B4.x); sdt += dt4.x;
            h = fmaf(exp2f(dt4.y * An), h, (dt4.y * u4.y) * B4.y); sdt += dt4.y;
            h = fmaf(exp2f(dt4.z * An), h, (dt4.z * u4.z) * B4.z); sdt += dt4.z;
            h = fmaf(exp2f(dt4.w * An), h, (dt4.w * u4.w) * B4.w); sdt += dt4.w;
        }
    }
    hend [(size_t)wid * DS + lane] = h;
    prodA[(size_t)wid * DS + lane] = exp2f(An * sdt);
}

// Sep-mode phase1: dt + precomputed du streams, all restrict.
__global__ __launch_bounds__(256, 4) void scan_phase1_sep(
    const float* __restrict__ dtT, const float* __restrict__ duT,
    const float4* __restrict__ bc4, const float* __restrict__ A_log,
    float* __restrict__ hend, float* __restrict__ prodA)
{
    const int wid  = __builtin_amdgcn_readfirstlane(
                        (int)((blockIdx.x * 256 + threadIdx.x) >> 6));
    const int lane = threadIdx.x & 63;
    const int c  = wid & (NC - 1);
    const int bd = wid >> 3;
    const int b  = bd / DI;
    const int d  = bd - b * DI;

    const float An = -expf(A_log[d * DS + lane]) * LOG2E;
    const float* dtp = dtT + (size_t)bd * SEQ + c * TCH;
    const float* dup = duT + (size_t)bd * SEQ + c * TCH;
    const float4* Bp = bc4 + ((size_t)b * (SEQ / 4) + c * (TCH / 4)) * 128 + lane;

    float h = 0.f, sdt = 0.f;
    for (int tb = 0; tb < TCH; tb += 16) {
#pragma unroll
        for (int g = 0; g < 4; g++) {
            const float4 B4  = Bp[(size_t)(tb / 4 + g) * 128];
            const float4 dt4 = *(const float4*)(dtp + tb + 4 * g);
            const float4 du4 = *(const float4*)(dup + tb + 4 * g);
            h = fmaf(exp2f(dt4.x * An), h, du4.x * B4.x); sdt += dt4.x;
            h = fmaf(exp2f(dt4.y * An), h, du4.y * B4.y); sdt += dt4.y;
            h = fmaf(exp2f(dt4.z * An), h, du4.z * B4.z); sdt += dt4.z;
            h = fmaf(exp2f(dt4.w * An), h, du4.w * B4.w); sdt += dt4.w;
        }
    }
    hend [(size_t)wid * DS + lane] = h;
    prodA[(size_t)wid * DS + lane] = exp2f(An * sdt);
}

__global__ __launch_bounds__(256) void scan_phase2(
    float* __restrict__ hend, float* __restrict__ prodA)
{
    const int bd   = (blockIdx.x * 256 + threadIdx.x) >> 6;
    const int lane = threadIdx.x & 63;
    float h = 0.f;
#pragma unroll
    for (int c = 0; c < NC; c++) {
        const size_t off = ((size_t)bd * NC + c) * DS + lane;
        const float pA = prodA[off];
        const float he = hend[off];
        prodA[off] = h;
        h = fmaf(pA, h, he);
    }
}

// Fallback (in-place) phase3: writes s over dtT (proven path).
__global__ __launch_bounds__(256, 4) void scan_phase3_inp(
    float* dtsT,
    const float* __restrict__ uT, const float4* __restrict__ bc4,
    const float* __restrict__ A_log, const float* __restrict__ hin)
{
    __shared__ float red[4][16 * 65];
    const int wid  = __builtin_amdgcn_readfirstlane(
                        (int)((blockIdx.x * 256 + threadIdx.x) >> 6));
    const int lane = threadIdx.x & 63;
    const int c  = wid & (NC - 1);
    const int bd = wid >> 3;
    const int b  = bd / DI;
    const int d  = bd - b * DI;

    const float An = -expf(A_log[d * DS + lane]) * LOG2E;
    float* dtp = dtsT + (size_t)bd * SEQ + c * TCH;
    const float* up  = uT  + (size_t)bd * SEQ + c * TCH;
    const float4* Bp = bc4 + ((size_t)b * (SEQ / 4) + c * (TCH / 4)) * 128 + lane;
    const float4* Cp = Bp + 64;
    float* slab = &red[threadIdx.x >> 6][0];
    const int tt = lane & 15, seg = lane >> 4;

    float4 Bc[4], Cc[4], Bn[4], Cn[4];
#pragma unroll
    for (int g = 0; g < 4; g++) {
        Bc[g] = Bp[(size_t)g * 128];
        Cc[g] = Cp[(size_t)g * 128];
    }

    float h = hin[(size_t)wid * DS + lane];
    for (int tb = 0; tb < TCH; tb += 16) {
        if (tb + 16 < TCH) {
#pragma unroll
            for (int g = 0; g < 4; g++) {
                Bn[g] = Bp[(size_t)(tb / 4 + 4 + g) * 128];
                Cn[g] = Cp[(size_t)(tb / 4 + 4 + g) * 128];
            }
        }
        float p[16];
#pragma unroll
        for (int g = 0; g < 4; g++) {
            const float4 dt4 = *(const float4*)(dtp + tb + 4 * g);
            const float4 u4  = *(const float4*)(up  + tb + 4 * g);
            h = fmaf(exp2f(dt4.x * An), h, (dt4.x * u4.x) * Bc[g].x); p[4*g+0] = h * Cc[g].x;
            h = fmaf(exp2f(dt4.y * An), h, (dt4.y * u4.y) * Bc[g].y); p[4*g+1] = h * Cc[g].y;
            h = fmaf(exp2f(dt4.z * An), h, (dt4.z * u4.z) * Bc[g].z); p[4*g+2] = h * Cc[g].z;
            h = fmaf(exp2f(dt4.w * An), h, (dt4.w * u4.w) * Bc[g].w); p[4*g+3] = h * Cc[g].w;
        }
#pragma unroll
        for (int i = 0; i < 16; i++) slab[i * 65 + lane] = p[i];
        float s = 0.f;
#pragma unroll
        for (int j = 0; j < 16; j++) s += slab[tt * 65 + seg * 16 + j];
        s += __shfl_xor(s, 16, 64);
        s += __shfl_xor(s, 32, 64);
        if (lane < 16) dtp[tb + tt] = s;
#pragma unroll
        for (int g = 0; g < 4; g++) { Bc[g] = Bn[g]; Cc[g] = Cn[g]; }
    }
}

// Sep-mode phase3: separate sT output, precomputed du, all restrict.
__global__ __launch_bounds__(256, 4) void scan_phase3_sep(
    const float* __restrict__ dtT, const float* __restrict__ duT,
    const float4* __restrict__ bc4, const float* __restrict__ A_log,
    const float* __restrict__ hin, float* __restrict__ sT)
{
    __shared__ float red[4][16 * 65];
    const int wid  = __builtin_amdgcn_readfirstlane(
                        (int)((blockIdx.x * 256 + threadIdx.x) >> 6));
    const int lane = threadIdx.x & 63;
    const int c  = wid & (NC - 1);
    const int bd = wid >> 3;
    const int b  = bd / DI;
    const int d  = bd - b * DI;

    const float An = -expf(A_log[d * DS + lane]) * LOG2E;
    const float* dtp = dtT + (size_t)bd * SEQ + c * TCH;
    const float* dup = duT + (size_t)bd * SEQ + c * TCH;
    const float4* Bp = bc4 + ((size_t)b * (SEQ / 4) + c * (TCH / 4)) * 128 + lane;
    const float4* Cp = Bp + 64;
    float* sp = sT + (size_t)bd * SEQ + c * TCH;
    float* slab = &red[threadIdx.x >> 6][0];
    const int tt = lane & 15, seg = lane >> 4;

    float h = hin[(size_t)wid * DS + lane];
    for (int tb = 0; tb < TCH; tb += 16) {
        float p[16];
#pragma unroll
        for (int g = 0; g < 4; g++) {
            const float4 B4  = Bp[(size_t)(tb / 4 + g) * 128];
            const float4 C4  = Cp[(size_t)(tb / 4 + g) * 128];
            const float4 dt4 = *(const float4*)(dtp + tb + 4 * g);
            const float4 du4 = *(const float4*)(dup + tb + 4 * g);
            h = fmaf(exp2f(dt4.x * An), h, du4.x * B4.x); p[4*g+0] = h * C4.x;
            h = fmaf(exp2f(dt4.y * An), h, du4.y * B4.y); p[4*g+1] = h * C4.y;
            h = fmaf(exp2f(dt4.z * An), h, du4.z * B4.z); p[4*g+2] = h * C4.z;
            h = fmaf(exp2f(dt4.w * An), h, du4.w * B4.w); p[4*g+3] = h * C4.w;
        }
#pragma unroll
        for (int i = 0; i < 16; i++) slab[i * 65 + lane] = p[i];
        float s = 0.f;
#pragma unroll
        for (int j = 0; j < 16; j++) s += slab[tt * 65 + seg * 16 + j];
        s += __shfl_xor(s, 16, 64);
        s += __shfl_xor(s, 32, 64);
        if (lane < 16) sp[tb + tt] = s;
    }
}

// Gate + bf16-split, packed into the dead xz[:, 0:DI] region:
//   yh(r,c) at ypack[r*6144 + c], yl(r,c) at ypack[r*6144 + 1536 + c].
__global__ __launch_bounds__(256) void gate_split(
    const float* __restrict__ sT, const float* __restrict__ uT,
    const float* __restrict__ Dskip, const float* zbase,  // xz (z half read)
    ushort_t* ypack)                                      // xz (y half written)
{
    __shared__ float ts[64][65];
    __shared__ float tu[64][65];
    const int tid = threadIdx.x;
    const int d0 = blockIdx.x * 64, t0 = blockIdx.y * 64, b = blockIdx.z;
    const int cl = tid & 63, q = tid >> 6;
#pragma unroll
    for (int i = 0; i < 16; i++) {
        const int d = q * 16 + i;
        const size_t off = ((size_t)b * DI + d0 + d) * SEQ + t0 + cl;
        ts[cl][d] = sT[off];
        tu[cl][d] = uT[off];
    }
    __syncthreads();
    const float Dd = Dskip[d0 + cl];
#pragma unroll
    for (int i = 0; i < 16; i++) {
        const int t = q * 16 + i;
        const size_t row = (size_t)b * SEQ + t0 + t;
        const float z = zbase[row * (2 * DI) + DI + d0 + cl];
        const float y = (ts[t][cl] + Dd * tu[t][cl]) * silu_fast(z);
        ushort_t h, l;
        bf16_split(y, h, l);
        ypack[row * 6144 + d0 + cl] = h;
        ypack[row * 6144 + 1536 + d0 + cl] = l;
    }
}

extern "C" void kernel_launch(void* const* d_in, const int* in_sizes, int n_in,
                              void* d_out, int out_size, void* d_ws, size_t ws_size,
                              hipStream_t stream) {
    (void)in_sizes; (void)n_in; (void)out_size;
    const float* x    = (const float*)d_in[0];
    const float* Wi   = (const float*)d_in[1];
    const float* cw   = (const float*)d_in[2];
    const float* cb   = (const float*)d_in[3];
    const float* Wx   = (const float*)d_in[4];
    const float* Wdt  = (const float*)d_in[5];
    const float* bdt  = (const float*)d_in[6];
    const float* Alog = (const float*)d_in[7];
    const float* Dsk  = (const float*)d_in[8];
    const float* Wo   = (const float*)d_in[9];
    float* out = (float*)d_out;

    // Workspace (fp32):
    float* xz    = (float*)d_ws;                          // [MROWS, 3072]; y-half becomes packed bf16 planes
    float* uT    = xz    + (size_t)MROWS * (2 * DI);      // [B*DI, SEQ]; also sh/sl arena (pre-conv)
    float* dtT   = uT    + (size_t)MROWS * DI;            // [B*DI, SEQ]; also wih/wil arena (pre-transpose)
    float* xdbl  = dtT   + (size_t)MROWS * DI;            // [MROWS, 176]; also woh/wol arena (post-gemm_dt)
    float* bcT   = xdbl  + (size_t)MROWS * XDC;           // [B][SEQ/4][128][4] interleaved
    float* xnext = bcT   + (size_t)BATCH * 128 * SEQ;     // [MROWS, 768]
    float* hend  = xnext;                                 // [B*DI*NC, DS] (aliases xnext)
    float* prodA = xnext + (size_t)BATCH * DI * NC * DS;  // [B*DI*NC, DS]
    float* wsend = xnext + (size_t)MROWS * DM;

    // Optional separate-buffer region (sep mode): sT + duT, 100.7 MB extra.
    const size_t base_bytes  = (size_t)((char*)wsend - (char*)d_ws);
    const size_t extra_bytes = (size_t)2 * MROWS * DI * sizeof(float);
    const bool sep = ws_size >= base_bytes + extra_bytes;
    float* sT_sep = wsend;
    float* duT    = wsend + (size_t)MROWS * DI;

    // bf16 plane homes (disjoint lifetimes):
    ushort_t* sh  = (ushort_t*)uT;                        // [MROWS, DM] x2 (25.2 MB <= 50.3)
    ushort_t* sl  = sh  + (size_t)MROWS * DM;
    ushort_t* wih = (ushort_t*)dtT;                       // [2*DI, DM] x2 (9.4 MB <= 50.3)
    ushort_t* wil = wih + (size_t)2 * DI * DM;
    ushort_t* woh = (ushort_t*)xdbl;                      // [DM, DI] x2 (4.7 MB <= 5.8)
    ushort_t* wol = woh + (size_t)DM * DI;
    ushort_t* ypk = (ushort_t*)xz;                        // packed y planes in xz[:, 0:DI]

    const float* src = x;
    for (int i = 0; i < DEPTH; i++) {
        const float* Wi_l   = Wi   + (size_t)i * 2 * DI * DM;
        const float* cw_l   = cw   + (size_t)i * DI * DC;
        const float* cb_l   = cb   + (size_t)i * DI;
        const float* Wx_l   = Wx   + (size_t)i * XDC * DI;
        const float* Wdt_l  = Wdt  + (size_t)i * DI * DTR;
        const float* bdt_l  = bdt  + (size_t)i * DI;
        const float* Alog_l = Alog + (size_t)i * DI * DS;
        const float* Dsk_l  = Dsk  + (size_t)i * DI;
        const float* Wo_l   = Wo   + (size_t)i * DM * DI;
        float* dst = (i == DEPTH - 1) ? out : xnext;

        // 1. split src and Wi to bf16 hi/lo planes
        split_bf16<<<(size_t)MROWS * DM / 1024, 256, 0, stream>>>(src, sh, sl);
        split_bf16<<<(size_t)2 * DI * DM / 1024, 256, 0, stream>>>(Wi_l, wih, wil);
        // 2. xz = src @ Wi^T  (bf16x2 MFMA)        [8192, 3072]
        gemm_mfma<<<dim3(2 * DI / 128, MROWS / 128), 256, 0, stream>>>(
            sh, sl, wih, wil, xz, 2 * DI, DM, DM, DM);
        // 3. uT = silu(conv(xz[:, :DI])) transposed [b][d][t] (overwrites sh/sl)
        conv_silu_T<<<dim3(DI / 64, SEQ / 64, BATCH), 256, 0, stream>>>(
            xz, cw_l, cb_l, uT);
        // 4. xdbl = u @ Wx^T via k-major uT        [8192, 176]
        gemm_tn<<<dim3((XDC + 127) / 128, MROWS / 128), 256, 0, stream>>>(
            uT, Wx_l, xdbl, XDC, XDC, DI);
        // 5. B/C -> lane-interleaved bc4 layout
        trans_bc_i4<<<dim3(2, SEQ / 64, BATCH), 256, 0, stream>>>(
            xdbl, (float4*)bcT);
        // 6. dt = softplus(xdbl[:, :48] @ Wdt^T + bdt) -> xz[:, 0:DI]
        gemm_dt<<<dim3(DI / 128, MROWS / 128), 256, 0, stream>>>(
            xdbl, XDC, Wdt_l, bdt_l, xz, 2 * DI, DI, DTR);
        // 7-10. dt transpose (+du) and chunked scan
        if (sep) {
            dtdu_T<<<dim3(DI / 64, SEQ / 64, BATCH), 256, 0, stream>>>(
                xz, uT, dtT, duT);
            scan_phase1_sep<<<(BATCH * DI * NC) / 4, 256, 0, stream>>>(
                dtT, duT, (const float4*)bcT, Alog_l, hend, prodA);
            scan_phase2<<<(BATCH * DI) / 4, 256, 0, stream>>>(hend, prodA);
            scan_phase3_sep<<<(BATCH * DI * NC) / 4, 256, 0, stream>>>(
                dtT, duT, (const float4*)bcT, Alog_l, prodA, sT_sep);
        } else {
            trans_r2t<<<dim3(DI / 64, SEQ / 64, BATCH), 256, 0, stream>>>(
                xz, 2 * DI, 0, dtT, DI);
            scan_phase1<<<(BATCH * DI * NC) / 4, 256, 0, stream>>>(
                dtT, uT, (const float4*)bcT, Alog_l, hend, prodA);
            scan_phase2<<<(BATCH * DI) / 4, 256, 0, stream>>>(hend, prodA);
            scan_phase3_inp<<<(BATCH * DI * NC) / 4, 256, 0, stream>>>(
                dtT, uT, (const float4*)bcT, Alog_l, prodA);
        }
        // 11. gate + bf16 split, packed into xz[:, 0:DI]
        gate_split<<<dim3(DI / 64, SEQ / 64, BATCH), 256, 0, stream>>>(
            sep ? sT_sep : dtT, uT, Dsk_l, xz, ypk);
        // 12. split Wo planes (xdbl region, dead)
        split_bf16<<<(size_t)DM * DI / 1024, 256, 0, stream>>>(Wo_l, woh, wol);
        // 13. dst = y @ Wo^T  (bf16x2 MFMA, packed-A layout)
        gemm_mfma<<<dim3(DM / 128, MROWS / 128), 256, 0, stream>>>(
            ypk, ypk + 1536, woh, wol, dst, DM, DI, 6144, DI);

        src = dst;
    }
}

// Round 9
// 1835.559 us; speedup vs baseline: 1.3689x; 1.3689x over previous
//
#include <hip/hip_runtime.h>
#include <hip/hip_bf16.h>
#include <math.h>

// Problem constants (MambaStack reference)
#define DEPTH   2
#define DM      768      // d_model
#define DS      64       // d_state
#define DC      4        // d_conv
#define DI      1536     // d_inner
#define DTR     48       // dt_rank
#define BATCH   4
#define SEQ     2048
#define MROWS   (BATCH*SEQ)          // 8192
#define XDC     (DTR + 2*DS)         // 176 (xdbl cols)
#define NC      8                    // scan chunks
#define TCH     (SEQ/NC)             // 256 timesteps per chunk
#define LOG2E   1.44269504088896f

typedef __attribute__((ext_vector_type(8))) short bf16x8;
typedef __attribute__((ext_vector_type(4))) float f32x4;
typedef unsigned short ushort_t;
#define GAS __attribute__((address_space(1)))
#define LAS __attribute__((address_space(3)))

__device__ __forceinline__ float silu_fast(float x) {
    return x / (1.f + __expf(-x));
}
__device__ __forceinline__ float softplus_acc(float x) {
    return x > 20.f ? x : log1pf(expf(x));
}

// Split fp32 -> (hi, lo) bf16 pair, both RNE.  hi+lo represents f to ~2^-17.
__device__ __forceinline__ void bf16_split(float f, ushort_t& h, ushort_t& l) {
    unsigned u = __float_as_uint(f);
    unsigned hr = u + 0x7FFF + ((u >> 16) & 1);
    h = (ushort_t)(hr >> 16);
    float lof = f - __uint_as_float((unsigned)h << 16);
    unsigned ul = __float_as_uint(lof);
    unsigned lr = ul + 0x7FFF + ((ul >> 16) & 1);
    l = (ushort_t)(lr >> 16);
}

// Contiguous fp32 array -> hi/lo bf16 planes.  n multiple of 1024.
__global__ __launch_bounds__(256) void split_bf16(
    const float* __restrict__ in, ushort_t* __restrict__ hi,
    ushort_t* __restrict__ lo)
{
    const size_t i = ((size_t)blockIdx.x * 256 + threadIdx.x) * 4;
    const float4 v = *(const float4*)(in + i);
    ushort4 h, l;
    bf16_split(v.x, h.x, l.x); bf16_split(v.y, h.y, l.y);
    bf16_split(v.z, h.z, l.z); bf16_split(v.w, h.w, l.w);
    *(ushort4*)(hi + i) = h;
    *(ushort4*)(lo + i) = l;
}

// ---------------- bf16x2-split MFMA GEMM ----------------
// C[M,N] = (Ah+Al) @ (Wh+Wl)^T, planes bf16, row strides ldA/ldW (elements).
// 128x128 tile, BK=32, 4 waves; 16x16x32 MFMA, 3 per tile (hh, hl, lh).
__global__ __launch_bounds__(256, 2) void gemm_mfma(
    const ushort_t* __restrict__ Ah, const ushort_t* __restrict__ Al,
    const ushort_t* __restrict__ Wh, const ushort_t* __restrict__ Wl,
    float* __restrict__ C, int N, int K, int ldA, int ldW)
{
    __shared__ ushort_t lds[4][128 * 32];
    const int tid  = threadIdx.x;
    const int wave = tid >> 6, lane = tid & 63;
    const int bm0 = blockIdx.y * 128, bn0 = blockIdx.x * 128;
    const int wm = (wave >> 1) * 64, wn = (wave & 1) * 64;

    const ushort_t* gp = (wave == 0) ? Ah : (wave == 1) ? Al : (wave == 2) ? Wh : Wl;
    const int ldg = (wave < 2) ? ldA : ldW;
    const int rb = (wave < 2) ? bm0 : bn0;
    const int srow = lane >> 2;           // 0..15
    const int skq  = (lane & 3) * 8;      // k offset in elements

    f32x4 acc[4][4];
#pragma unroll
    for (int i = 0; i < 4; i++)
#pragma unroll
        for (int j = 0; j < 4; j++) acc[i][j] = (f32x4){0.f, 0.f, 0.f, 0.f};

    const int lm  = lane & 15;
    const int kg8 = (lane >> 4) * 8;

    for (int k0 = 0; k0 < K; k0 += 32) {
#pragma unroll
        for (int j = 0; j < 8; j++) {
            const ushort_t* ga = gp + (size_t)(rb + j * 16 + srow) * ldg + k0 + skq;
            __builtin_amdgcn_global_load_lds(
                (const GAS unsigned*)ga, (LAS unsigned*)&lds[wave][j * 512], 16, 0, 0);
        }
        __syncthreads();

        bf16x8 ah[4], al[4], bh[4], bl[4];
#pragma unroll
        for (int i = 0; i < 4; i++) {
            const int ar = (wm + i * 16 + lm) * 32 + kg8;
            ah[i] = *(const bf16x8*)&lds[0][ar];
            al[i] = *(const bf16x8*)&lds[1][ar];
            const int br = (wn + i * 16 + lm) * 32 + kg8;
            bh[i] = *(const bf16x8*)&lds[2][br];
            bl[i] = *(const bf16x8*)&lds[3][br];
        }
#pragma unroll
        for (int mi = 0; mi < 4; mi++)
#pragma unroll
            for (int ni = 0; ni < 4; ni++) {
                f32x4 t = acc[mi][ni];
                t = __builtin_amdgcn_mfma_f32_16x16x32_bf16(al[mi], bh[ni], t, 0, 0, 0);
                t = __builtin_amdgcn_mfma_f32_16x16x32_bf16(ah[mi], bl[ni], t, 0, 0, 0);
                t = __builtin_amdgcn_mfma_f32_16x16x32_bf16(ah[mi], bh[ni], t, 0, 0, 0);
                acc[mi][ni] = t;
            }
        __syncthreads();
    }

#pragma unroll
    for (int mi = 0; mi < 4; mi++)
#pragma unroll
        for (int ni = 0; ni < 4; ni++)
#pragma unroll
            for (int r = 0; r < 4; r++) {
                const int rowg = bm0 + wm + mi * 16 + (lane >> 4) * 4 + r;
                const int colg = bn0 + wn + ni * 16 + lm;
                C[(size_t)rowg * N + colg] = acc[mi][ni][r];
            }
}

// Split-K gemm_tn: Cpart[z][M,N] = A_z @ W_z^T over k in [z*KS, (z+1)*KS).
// A is K-MAJOR per batch: AT[(b*K + k)*SEQ + t].  N=176 gives only 128 blocks
// at full-K; split-K=4 -> 512 blocks to cover 256 CUs.
__global__ __launch_bounds__(256, 2) void gemm_tn_sk(
    const float* __restrict__ AT,
    const float* __restrict__ W,
    float* __restrict__ Cpart, int ldC,
    int N, int K, int KS)
{
    __shared__ float As[8][132];
    __shared__ float Bs[8][132];
    const int tid = threadIdx.x;
    const int bm0 = blockIdx.y * 128;
    const int bn0 = blockIdx.x * 128;
    const int kb  = blockIdx.z * KS;
    const int bb  = bm0 / SEQ;
    const int t0  = bm0 - bb * SEQ;
    const int tx = tid & 15;
    const int ty = tid >> 4;
    const int arow = tid >> 5;
    const int am4  = (tid & 31) * 4;
    const int lrow = tid >> 1;
    const int lk4  = (tid & 1) * 4;
    float* C = Cpart + (size_t)blockIdx.z * MROWS * ldC;

    float acc[8][8];
#pragma unroll
    for (int i = 0; i < 8; i++)
#pragma unroll
        for (int j = 0; j < 8; j++) acc[i][j] = 0.f;

    for (int k0 = kb; k0 < kb + KS; k0 += 8) {
        const float4 av = *(const float4*)(AT + ((size_t)(bb * K + k0 + arow)) * SEQ + t0 + am4);
        float4 wv;
        const int wrow = bn0 + lrow;
        if (wrow < N) wv = *(const float4*)(W + (size_t)wrow * K + (k0 + lk4));
        else          wv = make_float4(0.f, 0.f, 0.f, 0.f);
        __syncthreads();
        *(float4*)&As[arow][am4] = av;
        Bs[lk4 + 0][lrow] = wv.x; Bs[lk4 + 1][lrow] = wv.y;
        Bs[lk4 + 2][lrow] = wv.z; Bs[lk4 + 3][lrow] = wv.w;
        __syncthreads();
#pragma unroll
        for (int kk = 0; kk < 8; kk++) {
            const float4 a0 = *(const float4*)&As[kk][ty * 8];
            const float4 a1 = *(const float4*)&As[kk][ty * 8 + 4];
            const float4 b0 = *(const float4*)&Bs[kk][tx * 8];
            const float4 b1 = *(const float4*)&Bs[kk][tx * 8 + 4];
            const float ar[8] = {a0.x, a0.y, a0.z, a0.w, a1.x, a1.y, a1.z, a1.w};
            const float br[8] = {b0.x, b0.y, b0.z, b0.w, b1.x, b1.y, b1.z, b1.w};
#pragma unroll
            for (int i = 0; i < 8; i++)
#pragma unroll
                for (int j = 0; j < 8; j++)
                    acc[i][j] = fmaf(ar[i], br[j], acc[i][j]);
        }
    }

#pragma unroll
    for (int i = 0; i < 8; i++) {
        const int row = bm0 + ty * 8 + i;
#pragma unroll
        for (int j4 = 0; j4 < 8; j4 += 4) {
            const int col = bn0 + tx * 8 + j4;
            if (col + 3 < N) {
                *(float4*)(C + (size_t)row * ldC + col) =
                    make_float4(acc[i][j4], acc[i][j4 + 1], acc[i][j4 + 2], acc[i][j4 + 3]);
            }
        }
    }
}

// Sum the 4 split-K partials into xdbl.
__global__ __launch_bounds__(256) void reduce4(
    const float* __restrict__ parts, float* __restrict__ out)
{
    const size_t i = ((size_t)blockIdx.x * 256 + threadIdx.x) * 4;
    const size_t S = (size_t)MROWS * XDC;
    float4 a = *(const float4*)(parts + i);
    const float4 b = *(const float4*)(parts + S + i);
    const float4 c = *(const float4*)(parts + 2 * S + i);
    const float4 d = *(const float4*)(parts + 3 * S + i);
    a.x += b.x + c.x + d.x;  a.y += b.y + c.y + d.y;
    a.z += b.z + c.z + d.z;  a.w += b.w + c.w + d.w;
    *(float4*)(out + i) = a;
}

// dt GEMM (small K=48): C = softplus(A[:, :48] @ W^T + bias), row-major.
__global__ __launch_bounds__(256, 2) void gemm_dt(
    const float* __restrict__ A, int ldA,
    const float* __restrict__ W,
    const float* __restrict__ bias,
    float* __restrict__ C, int ldC,
    int N, int K)
{
    __shared__ float As[8][132];
    __shared__ float Bs[8][132];
    const int tid = threadIdx.x;
    const int bm0 = blockIdx.y * 128;
    const int bn0 = blockIdx.x * 128;
    const int tx = tid & 15;
    const int ty = tid >> 4;
    const int lrow = tid >> 1;
    const int lk4  = (tid & 1) * 4;

    float acc[8][8];
#pragma unroll
    for (int i = 0; i < 8; i++)
#pragma unroll
        for (int j = 0; j < 8; j++) acc[i][j] = 0.f;

    for (int k0 = 0; k0 < K; k0 += 8) {
        const float4 av = *(const float4*)(A + (size_t)(bm0 + lrow) * ldA + (k0 + lk4));
        float4 wv;
        const int wrow = bn0 + lrow;
        if (wrow < N) wv = *(const float4*)(W + (size_t)wrow * K + (k0 + lk4));
        else          wv = make_float4(0.f, 0.f, 0.f, 0.f);
        __syncthreads();
        As[lk4 + 0][lrow] = av.x; As[lk4 + 1][lrow] = av.y;
        As[lk4 + 2][lrow] = av.z; As[lk4 + 3][lrow] = av.w;
        Bs[lk4 + 0][lrow] = wv.x; Bs[lk4 + 1][lrow] = wv.y;
        Bs[lk4 + 2][lrow] = wv.z; Bs[lk4 + 3][lrow] = wv.w;
        __syncthreads();
#pragma unroll
        for (int kk = 0; kk < 8; kk++) {
            const float4 a0 = *(const float4*)&As[kk][ty * 8];
            const float4 a1 = *(const float4*)&As[kk][ty * 8 + 4];
            const float4 b0 = *(const float4*)&Bs[kk][tx * 8];
            const float4 b1 = *(const float4*)&Bs[kk][tx * 8 + 4];
            const float ar[8] = {a0.x, a0.y, a0.z, a0.w, a1.x, a1.y, a1.z, a1.w};
            const float br[8] = {b0.x, b0.y, b0.z, b0.w, b1.x, b1.y, b1.z, b1.w};
#pragma unroll
            for (int i = 0; i < 8; i++)
#pragma unroll
                for (int j = 0; j < 8; j++)
                    acc[i][j] = fmaf(ar[i], br[j], acc[i][j]);
        }
    }

#pragma unroll
    for (int i = 0; i < 8; i++) {
        const int row = bm0 + ty * 8 + i;
#pragma unroll
        for (int j4 = 0; j4 < 8; j4 += 4) {
            const int col = bn0 + tx * 8 + j4;
            if (col + 3 < N) {
                float4 v = make_float4(acc[i][j4], acc[i][j4 + 1], acc[i][j4 + 2], acc[i][j4 + 3]);
                v.x = softplus_acc(v.x + bias[col + 0]);
                v.y = softplus_acc(v.y + bias[col + 1]);
                v.z = softplus_acc(v.z + bias[col + 2]);
                v.w = softplus_acc(v.w + bias[col + 3]);
                *(float4*)(C + (size_t)row * ldC + col) = v;
            }
        }
    }
}

// Depthwise causal conv (K=4) + SiLU -> uT [b][d][t] only.
__global__ __launch_bounds__(256) void conv_silu_T(
    const float* __restrict__ xz, const float* __restrict__ cw,
    const float* __restrict__ cb, float* __restrict__ uT)
{
    __shared__ float tin[67][65];
    __shared__ float ttr[64][65];
    const int tid = threadIdx.x;
    const int d0 = blockIdx.x * 64, t0 = blockIdx.y * 64, b = blockIdx.z;
    const int cl = tid & 63, q = tid >> 6;

    for (int r = q; r < 67; r += 4) {
        const int t = t0 - 3 + r;
        float v = 0.f;
        if (t >= 0) v = xz[((size_t)b * SEQ + t) * (2 * DI) + d0 + cl];
        tin[r][cl] = v;
    }
    __syncthreads();

    const float4 w = ((const float4*)cw)[d0 + cl];
    const float bb = cb[d0 + cl];
#pragma unroll
    for (int i = 0; i < 16; i++) {
        const int t = q * 16 + i;
        float a = bb;
        a = fmaf(tin[t + 0][cl], w.x, a);
        a = fmaf(tin[t + 1][cl], w.y, a);
        a = fmaf(tin[t + 2][cl], w.z, a);
        a = fmaf(tin[t + 3][cl], w.w, a);
        ttr[cl][t] = silu_fast(a);
    }
    __syncthreads();
#pragma unroll
    for (int i = 0; i < 16; i++) {
        const int d = q * 16 + i;
        uT[((size_t)b * DI + d0 + d) * SEQ + t0 + cl] = ttr[d][cl];
    }
}

// Tiled transpose: in[row=b*SEQ+t, coloff+c] (ld ldin) -> out[(b*ncols+c)*SEQ + t]
__global__ __launch_bounds__(256) void trans_r2t(
    const float* __restrict__ in, int ldin, int coloff,
    float* __restrict__ out, int ncols)
{
    __shared__ float tile[64][65];
    const int tid = threadIdx.x;
    const int c0 = blockIdx.x * 64, t0 = blockIdx.y * 64, b = blockIdx.z;
    const int cl = tid & 63, q = tid >> 6;
#pragma unroll
    for (int i = 0; i < 16; i++) {
        const int r = q * 16 + i;
        tile[r][cl] = in[((size_t)b * SEQ + t0 + r) * ldin + coloff + c0 + cl];
    }
    __syncthreads();
#pragma unroll
    for (int i = 0; i < 16; i++) {
        const int cc = q * 16 + i;
        out[((size_t)b * ncols + c0 + cc) * SEQ + t0 + cl] = tile[cl][cc];
    }
}

// B/C transpose into lane-interleaved layout:
//   bc4[(b*(SEQ/4) + t/4)*128 + ch] = float4{ x[t..t+3][ch] }
__global__ __launch_bounds__(256) void trans_bc_i4(
    const float* __restrict__ in, float4* __restrict__ bc4)
{
    __shared__ float tile[64][65];
    const int tid = threadIdx.x;
    const int c0 = blockIdx.x * 64, t0 = blockIdx.y * 64, b = blockIdx.z;
    const int cl = tid & 63, q = tid >> 6;
#pragma unroll
    for (int i = 0; i < 16; i++) {
        const int r = q * 16 + i;
        tile[r][cl] = in[((size_t)b * SEQ + t0 + r) * XDC + DTR + c0 + cl];
    }
    __syncthreads();
#pragma unroll
    for (int i = 0; i < 4; i++) {
        const int j = q * 4 + i;
        const float4 v = make_float4(tile[4 * j + 0][cl], tile[4 * j + 1][cl],
                                     tile[4 * j + 2][cl], tile[4 * j + 3][cl]);
        bc4[((size_t)b * (SEQ / 4) + (t0 / 4 + j)) * 128 + c0 + cl] = v;
    }
}

// ---------------- Chunked selective scan ----------------
// All four streams (dt, u, B, C) software-pipelined one 16-t block ahead.

__global__ __launch_bounds__(256, 2) void scan_phase1(
    const float* __restrict__ dtT, const float* __restrict__ uT,
    const float4* __restrict__ bc4, const float* __restrict__ A_log,
    float* __restrict__ hend, float* __restrict__ prodA)
{
    const int wid  = __builtin_amdgcn_readfirstlane(
                        (int)((blockIdx.x * 256 + threadIdx.x) >> 6));
    const int lane = threadIdx.x & 63;
    const int c  = wid & (NC - 1);
    const int bd = wid >> 3;
    const int b  = bd / DI;
    const int d  = bd - b * DI;

    const float An = -expf(A_log[d * DS + lane]) * LOG2E;
    const float* dtp = dtT + (size_t)bd * SEQ + c * TCH;
    const float* up  = uT  + (size_t)bd * SEQ + c * TCH;
    const float4* Bp = bc4 + ((size_t)b * (SEQ / 4) + c * (TCH / 4)) * 128 + lane;

    float4 dtc[4], uc[4], Bc[4], dtn[4], un[4], Bn[4];
#pragma unroll
    for (int g = 0; g < 4; g++) {
        dtc[g] = *(const float4*)(dtp + 4 * g);
        uc[g]  = *(const float4*)(up  + 4 * g);
        Bc[g]  = Bp[(size_t)g * 128];
    }

    float h = 0.f, sdt = 0.f;
    for (int tb = 0; tb < TCH; tb += 16) {
        if (tb + 16 < TCH) {
#pragma unroll
            for (int g = 0; g < 4; g++) {
                dtn[g] = *(const float4*)(dtp + tb + 16 + 4 * g);
                un[g]  = *(const float4*)(up  + tb + 16 + 4 * g);
                Bn[g]  = Bp[(size_t)(tb / 4 + 4 + g) * 128];
            }
        }
#pragma unroll
        for (int g = 0; g < 4; g++) {
            h = fmaf(__builtin_amdgcn_exp2f(dtc[g].x * An), h, (dtc[g].x * uc[g].x) * Bc[g].x); sdt += dtc[g].x;
            h = fmaf(__builtin_amdgcn_exp2f(dtc[g].y * An), h, (dtc[g].y * uc[g].y) * Bc[g].y); sdt += dtc[g].y;
            h = fmaf(__builtin_amdgcn_exp2f(dtc[g].z * An), h, (dtc[g].z * uc[g].z) * Bc[g].z); sdt += dtc[g].z;
            h = fmaf(__builtin_amdgcn_exp2f(dtc[g].w * An), h, (dtc[g].w * uc[g].w) * Bc[g].w); sdt += dtc[g].w;
        }
#pragma unroll
        for (int g = 0; g < 4; g++) { dtc[g] = dtn[g]; uc[g] = un[g]; Bc[g] = Bn[g]; }
    }
    hend [(size_t)wid * DS + lane] = h;
    prodA[(size_t)wid * DS + lane] = __builtin_amdgcn_exp2f(An * sdt);
}

__global__ __launch_bounds__(256) void scan_phase2(
    float* __restrict__ hend, float* __restrict__ prodA)
{
    const int bd   = (blockIdx.x * 256 + threadIdx.x) >> 6;
    const int lane = threadIdx.x & 63;
    float h = 0.f;
#pragma unroll
    for (int c = 0; c < NC; c++) {
        const size_t off = ((size_t)bd * NC + c) * DS + lane;
        const float pA = prodA[off];
        const float he = hend[off];
        prodA[off] = h;
        h = fmaf(pA, h, he);
    }
}

// Phase 3: resumed scan; writes raw reduced s IN PLACE over dtT (each wave
// reads dt[tb+16) via prefetch strictly before storing s[tb); spans disjoint).
__global__ __launch_bounds__(256, 2) void scan_phase3(
    float* dtsT,                                   // in: dtT, out: sT (aliased!)
    const float* __restrict__ uT, const float4* __restrict__ bc4,
    const float* __restrict__ A_log, const float* __restrict__ hin)
{
    __shared__ float red[4][16 * 65];
    const int wid  = __builtin_amdgcn_readfirstlane(
                        (int)((blockIdx.x * 256 + threadIdx.x) >> 6));
    const int lane = threadIdx.x & 63;
    const int c  = wid & (NC - 1);
    const int bd = wid >> 3;
    const int b  = bd / DI;
    const int d  = bd - b * DI;

    const float An = -expf(A_log[d * DS + lane]) * LOG2E;
    float* dtp = dtsT + (size_t)bd * SEQ + c * TCH;
    const float* up  = uT  + (size_t)bd * SEQ + c * TCH;
    const float4* Bp = bc4 + ((size_t)b * (SEQ / 4) + c * (TCH / 4)) * 128 + lane;
    const float4* Cp = Bp + 64;
    float* slab = &red[threadIdx.x >> 6][0];
    const int tt = lane & 15, seg = lane >> 4;

    float4 dtc[4], uc[4], Bc[4], Cc[4], dtn[4], un[4], Bn[4], Cn[4];
#pragma unroll
    for (int g = 0; g < 4; g++) {
        dtc[g] = *(const float4*)(dtp + 4 * g);
        uc[g]  = *(const float4*)(up  + 4 * g);
        Bc[g]  = Bp[(size_t)g * 128];
        Cc[g]  = Cp[(size_t)g * 128];
    }

    float h = hin[(size_t)wid * DS + lane];
    for (int tb = 0; tb < TCH; tb += 16) {
        if (tb + 16 < TCH) {
#pragma unroll
            for (int g = 0; g < 4; g++) {
                dtn[g] = *(const float4*)(dtp + tb + 16 + 4 * g);
                un[g]  = *(const float4*)(up  + tb + 16 + 4 * g);
                Bn[g]  = Bp[(size_t)(tb / 4 + 4 + g) * 128];
                Cn[g]  = Cp[(size_t)(tb / 4 + 4 + g) * 128];
            }
        }
        float p[16];
#pragma unroll
        for (int g = 0; g < 4; g++) {
            h = fmaf(__builtin_amdgcn_exp2f(dtc[g].x * An), h, (dtc[g].x * uc[g].x) * Bc[g].x); p[4*g+0] = h * Cc[g].x;
            h = fmaf(__builtin_amdgcn_exp2f(dtc[g].y * An), h, (dtc[g].y * uc[g].y) * Bc[g].y); p[4*g+1] = h * Cc[g].y;
            h = fmaf(__builtin_amdgcn_exp2f(dtc[g].z * An), h, (dtc[g].z * uc[g].z) * Bc[g].z); p[4*g+2] = h * Cc[g].z;
            h = fmaf(__builtin_amdgcn_exp2f(dtc[g].w * An), h, (dtc[g].w * uc[g].w) * Bc[g].w); p[4*g+3] = h * Cc[g].w;
        }
        // wave-synchronous LDS transpose-reduce over the 64 states
#pragma unroll
        for (int i = 0; i < 16; i++) slab[i * 65 + lane] = p[i];
        float s = 0.f;
#pragma unroll
        for (int j = 0; j < 16; j++) s += slab[tt * 65 + seg * 16 + j];
        s += __shfl_xor(s, 16, 64);
        s += __shfl_xor(s, 32, 64);
        if (lane < 16) dtp[tb + tt] = s;
#pragma unroll
        for (int g = 0; g < 4; g++) {
            dtc[g] = dtn[g]; uc[g] = un[g]; Bc[g] = Bn[g]; Cc[g] = Cn[g];
        }
    }
}

// Gate + bf16-split, packed into the dead xz[:, 0:DI] region:
//   yh(r,c) at ypack[r*6144 + c], yl(r,c) at ypack[r*6144 + 1536 + c].
__global__ __launch_bounds__(256) void gate_split(
    const float* __restrict__ sT, const float* __restrict__ uT,
    const float* __restrict__ Dskip, const float* zbase,  // xz (z half read)
    ushort_t* ypack)                                      // xz (y half written)
{
    __shared__ float ts[64][65];
    __shared__ float tu[64][65];
    const int tid = threadIdx.x;
    const int d0 = blockIdx.x * 64, t0 = blockIdx.y * 64, b = blockIdx.z;
    const int cl = tid & 63, q = tid >> 6;
#pragma unroll
    for (int i = 0; i < 16; i++) {
        const int d = q * 16 + i;
        const size_t off = ((size_t)b * DI + d0 + d) * SEQ + t0 + cl;
        ts[cl][d] = sT[off];
        tu[cl][d] = uT[off];
    }
    __syncthreads();
    const float Dd = Dskip[d0 + cl];
#pragma unroll
    for (int i = 0; i < 16; i++) {
        const int t = q * 16 + i;
        const size_t row = (size_t)b * SEQ + t0 + t;
        const float z = zbase[row * (2 * DI) + DI + d0 + cl];
        const float y = (ts[t][cl] + Dd * tu[t][cl]) * silu_fast(z);
        ushort_t h, l;
        bf16_split(y, h, l);
        ypack[row * 6144 + d0 + cl] = h;
        ypack[row * 6144 + 1536 + d0 + cl] = l;
    }
}

extern "C" void kernel_launch(void* const* d_in, const int* in_sizes, int n_in,
                              void* d_out, int out_size, void* d_ws, size_t ws_size,
                              hipStream_t stream) {
    (void)in_sizes; (void)n_in; (void)out_size; (void)ws_size;
    const float* x    = (const float*)d_in[0];
    const float* Wi   = (const float*)d_in[1];
    const float* cw   = (const float*)d_in[2];
    const float* cb   = (const float*)d_in[3];
    const float* Wx   = (const float*)d_in[4];
    const float* Wdt  = (const float*)d_in[5];
    const float* bdt  = (const float*)d_in[6];
    const float* Alog = (const float*)d_in[7];
    const float* Dsk  = (const float*)d_in[8];
    const float* Wo   = (const float*)d_in[9];
    float* out = (float*)d_out;

    // Workspace (fp32), ~236 MB:
    float* xz    = (float*)d_ws;                          // [MROWS, 3072]; y-half becomes packed bf16 planes
    float* uT    = xz    + (size_t)MROWS * (2 * DI);      // [B*DI, SEQ]; also sh/sl arena (pre-conv)
    float* dtT   = uT    + (size_t)MROWS * DI;            // [B*DI, SEQ]; also wih/wil arena; sT after phase3
    float* xdbl  = dtT   + (size_t)MROWS * DI;            // [MROWS, 176]; also woh/wol arena (post-gemm_dt)
    float* bcT   = xdbl  + (size_t)MROWS * XDC;           // [B][SEQ/4][128][4] interleaved
    float* xnext = bcT   + (size_t)BATCH * 128 * SEQ;     // [MROWS, 768]
    // xnext triple-aliased, all lifetimes disjoint:
    //  (a) split-K partials for gemm_tn (step 4, consumed by reduce4 step 4.5)
    //  (b) hend/prodA during scan (steps 8-10)
    //  (c) layer-0 output dst (step 13), consumed only by layer-1 step 1
    float* parts = xnext;                                 // [4][MROWS, XDC] = 23.1 MB
    float* hend  = xnext;                                 // [B*DI*NC, DS]
    float* prodA = xnext + (size_t)BATCH * DI * NC * DS;  // [B*DI*NC, DS]

    // bf16 plane homes (disjoint lifetimes):
    ushort_t* sh  = (ushort_t*)uT;                        // [MROWS, DM] x2
    ushort_t* sl  = sh  + (size_t)MROWS * DM;
    ushort_t* wih = (ushort_t*)dtT;                       // [2*DI, DM] x2
    ushort_t* wil = wih + (size_t)2 * DI * DM;
    ushort_t* woh = (ushort_t*)xdbl;                      // [DM, DI] x2
    ushort_t* wol = woh + (size_t)DM * DI;
    ushort_t* ypk = (ushort_t*)xz;                        // packed y planes in xz[:, 0:DI]

    const float* src = x;
    for (int i = 0; i < DEPTH; i++) {
        const float* Wi_l   = Wi   + (size_t)i * 2 * DI * DM;
        const float* cw_l   = cw   + (size_t)i * DI * DC;
        const float* cb_l   = cb   + (size_t)i * DI;
        const float* Wx_l   = Wx   + (size_t)i * XDC * DI;
        const float* Wdt_l  = Wdt  + (size_t)i * DI * DTR;
        const float* bdt_l  = bdt  + (size_t)i * DI;
        const float* Alog_l = Alog + (size_t)i * DI * DS;
        const float* Dsk_l  = Dsk  + (size_t)i * DI;
        const float* Wo_l   = Wo   + (size_t)i * DM * DI;
        float* dst = (i == DEPTH - 1) ? out : xnext;

        // 1. split src and Wi to bf16 hi/lo planes
        split_bf16<<<(size_t)MROWS * DM / 1024, 256, 0, stream>>>(src, sh, sl);
        split_bf16<<<(size_t)2 * DI * DM / 1024, 256, 0, stream>>>(Wi_l, wih, wil);
        // 2. xz = src @ Wi^T  (bf16x2 MFMA)        [8192, 3072]
        gemm_mfma<<<dim3(2 * DI / 128, MROWS / 128), 256, 0, stream>>>(
            sh, sl, wih, wil, xz, 2 * DI, DM, DM, DM);
        // 3. uT = silu(conv(xz[:, :DI])) transposed [b][d][t] (overwrites sh/sl)
        conv_silu_T<<<dim3(DI / 64, SEQ / 64, BATCH), 256, 0, stream>>>(
            xz, cw_l, cb_l, uT);
        // 4. xdbl = u @ Wx^T via k-major uT, split-K=4 -> partials, then reduce
        gemm_tn_sk<<<dim3((XDC + 127) / 128, MROWS / 128, 4), 256, 0, stream>>>(
            uT, Wx_l, parts, XDC, XDC, DI, DI / 4);
        reduce4<<<(size_t)MROWS * XDC / 1024, 256, 0, stream>>>(parts, xdbl);
        // 5. B/C -> lane-interleaved bc4 layout
        trans_bc_i4<<<dim3(2, SEQ / 64, BATCH), 256, 0, stream>>>(
            xdbl, (float4*)bcT);
        // 6. dt = softplus(xdbl[:, :48] @ Wdt^T + bdt) -> xz[:, 0:DI]
        gemm_dt<<<dim3(DI / 128, MROWS / 128), 256, 0, stream>>>(
            xdbl, XDC, Wdt_l, bdt_l, xz, 2 * DI, DI, DTR);
        // 7. dt transpose -> dtT [b][d][t]
        trans_r2t<<<dim3(DI / 64, SEQ / 64, BATCH), 256, 0, stream>>>(
            xz, 2 * DI, 0, dtT, DI);
        // 8-10. chunked scan; phase3 writes raw s in place over dtT
        scan_phase1<<<(BATCH * DI * NC) / 4, 256, 0, stream>>>(
            dtT, uT, (const float4*)bcT, Alog_l, hend, prodA);
        scan_phase2<<<(BATCH * DI) / 4, 256, 0, stream>>>(hend, prodA);
        scan_phase3<<<(BATCH * DI * NC) / 4, 256, 0, stream>>>(
            dtT, uT, (const float4*)bcT, Alog_l, prodA);
        // 11. gate + bf16 split, packed into xz[:, 0:DI]
        gate_split<<<dim3(DI / 64, SEQ / 64, BATCH), 256, 0, stream>>>(
            dtT, uT, Dsk_l, xz, ypk);
        // 12. split Wo planes (xdbl region, dead)
        split_bf16<<<(size_t)DM * DI / 1024, 256, 0, stream>>>(Wo_l, woh, wol);
        // 13. dst = y @ Wo^T  (bf16x2 MFMA, packed-A layout)
        gemm_mfma<<<dim3(DM / 128, MROWS / 128), 256, 0, stream>>>(
            ypk, ypk + 1536, woh, wol, dst, DM, DI, 6144, DI);

        src = dst;
    }
}

// Round 10
// 1832.128 us; speedup vs baseline: 1.3715x; 1.0019x over previous
//
#include <hip/hip_runtime.h>
#include <hip/hip_bf16.h>
#include <math.h>

// Problem constants (MambaStack reference)
#define DEPTH   2
#define DM      768      // d_model
#define DS      64       // d_state
#define DC      4        // d_conv
#define DI      1536     // d_inner
#define DTR     48       // dt_rank
#define BATCH   4
#define SEQ     2048
#define MROWS   (BATCH*SEQ)          // 8192
#define XDC     (DTR + 2*DS)         // 176 (xdbl cols)
#define NC      8                    // scan chunks
#define TCH     (SEQ/NC)             // 256 timesteps per chunk
#define LOG2E   1.44269504088896f

typedef __attribute__((ext_vector_type(8))) short bf16x8;
typedef __attribute__((ext_vector_type(4))) float f32x4;
typedef unsigned short ushort_t;
#define GAS __attribute__((address_space(1)))
#define LAS __attribute__((address_space(3)))

__device__ __forceinline__ float silu_fast(float x) {
    return x / (1.f + __expf(-x));
}
__device__ __forceinline__ float softplus_acc(float x) {
    return x > 20.f ? x : log1pf(expf(x));
}

// Split fp32 -> (hi, lo) bf16 pair, both RNE.  hi+lo represents f to ~2^-17.
__device__ __forceinline__ void bf16_split(float f, ushort_t& h, ushort_t& l) {
    unsigned u = __float_as_uint(f);
    unsigned hr = u + 0x7FFF + ((u >> 16) & 1);
    h = (ushort_t)(hr >> 16);
    float lof = f - __uint_as_float((unsigned)h << 16);
    unsigned ul = __float_as_uint(lof);
    unsigned lr = ul + 0x7FFF + ((ul >> 16) & 1);
    l = (ushort_t)(lr >> 16);
}

// Contiguous fp32 array -> hi/lo bf16 planes.  n multiple of 1024.
__global__ __launch_bounds__(256) void split_bf16(
    const float* __restrict__ in, ushort_t* __restrict__ hi,
    ushort_t* __restrict__ lo)
{
    const size_t i = ((size_t)blockIdx.x * 256 + threadIdx.x) * 4;
    const float4 v = *(const float4*)(in + i);
    ushort4 h, l;
    bf16_split(v.x, h.x, l.x); bf16_split(v.y, h.y, l.y);
    bf16_split(v.z, h.z, l.z); bf16_split(v.w, h.w, l.w);
    *(ushort4*)(hi + i) = h;
    *(ushort4*)(lo + i) = l;
}

// ---------------- bf16x2-split MFMA GEMM ----------------
// C[M,N] = (Ah+Al) @ (Wh+Wl)^T, planes bf16, row strides ldA/ldW (elements).
// 128x128 tile, BK=32, 4 waves; 16x16x32 MFMA, 3 per tile (hh, hl, lh).
__global__ __launch_bounds__(256, 2) void gemm_mfma(
    const ushort_t* __restrict__ Ah, const ushort_t* __restrict__ Al,
    const ushort_t* __restrict__ Wh, const ushort_t* __restrict__ Wl,
    float* __restrict__ C, int N, int K, int ldA, int ldW)
{
    __shared__ ushort_t lds[4][128 * 32];
    const int tid  = threadIdx.x;
    const int wave = tid >> 6, lane = tid & 63;
    const int bm0 = blockIdx.y * 128, bn0 = blockIdx.x * 128;
    const int wm = (wave >> 1) * 64, wn = (wave & 1) * 64;

    const ushort_t* gp = (wave == 0) ? Ah : (wave == 1) ? Al : (wave == 2) ? Wh : Wl;
    const int ldg = (wave < 2) ? ldA : ldW;
    const int rb = (wave < 2) ? bm0 : bn0;
    const int srow = lane >> 2;           // 0..15
    const int skq  = (lane & 3) * 8;      // k offset in elements

    f32x4 acc[4][4];
#pragma unroll
    for (int i = 0; i < 4; i++)
#pragma unroll
        for (int j = 0; j < 4; j++) acc[i][j] = (f32x4){0.f, 0.f, 0.f, 0.f};

    const int lm  = lane & 15;
    const int kg8 = (lane >> 4) * 8;

    for (int k0 = 0; k0 < K; k0 += 32) {
#pragma unroll
        for (int j = 0; j < 8; j++) {
            const ushort_t* ga = gp + (size_t)(rb + j * 16 + srow) * ldg + k0 + skq;
            __builtin_amdgcn_global_load_lds(
                (const GAS unsigned*)ga, (LAS unsigned*)&lds[wave][j * 512], 16, 0, 0);
        }
        __syncthreads();

        bf16x8 ah[4], al[4], bh[4], bl[4];
#pragma unroll
        for (int i = 0; i < 4; i++) {
            const int ar = (wm + i * 16 + lm) * 32 + kg8;
            ah[i] = *(const bf16x8*)&lds[0][ar];
            al[i] = *(const bf16x8*)&lds[1][ar];
            const int br = (wn + i * 16 + lm) * 32 + kg8;
            bh[i] = *(const bf16x8*)&lds[2][br];
            bl[i] = *(const bf16x8*)&lds[3][br];
        }
#pragma unroll
        for (int mi = 0; mi < 4; mi++)
#pragma unroll
            for (int ni = 0; ni < 4; ni++) {
                f32x4 t = acc[mi][ni];
                t = __builtin_amdgcn_mfma_f32_16x16x32_bf16(al[mi], bh[ni], t, 0, 0, 0);
                t = __builtin_amdgcn_mfma_f32_16x16x32_bf16(ah[mi], bl[ni], t, 0, 0, 0);
                t = __builtin_amdgcn_mfma_f32_16x16x32_bf16(ah[mi], bh[ni], t, 0, 0, 0);
                acc[mi][ni] = t;
            }
        __syncthreads();
    }

#pragma unroll
    for (int mi = 0; mi < 4; mi++)
#pragma unroll
        for (int ni = 0; ni < 4; ni++)
#pragma unroll
            for (int r = 0; r < 4; r++) {
                const int rowg = bm0 + wm + mi * 16 + (lane >> 4) * 4 + r;
                const int colg = bn0 + wn + ni * 16 + lm;
                C[(size_t)rowg * N + colg] = acc[mi][ni][r];
            }
}

// Split-K gemm_tn: Cpart[z][M,N] = A_z @ W_z^T over k in [z*KS, (z+1)*KS).
__global__ __launch_bounds__(256, 2) void gemm_tn_sk(
    const float* __restrict__ AT,
    const float* __restrict__ W,
    float* __restrict__ Cpart, int ldC,
    int N, int K, int KS)
{
    __shared__ float As[8][132];
    __shared__ float Bs[8][132];
    const int tid = threadIdx.x;
    const int bm0 = blockIdx.y * 128;
    const int bn0 = blockIdx.x * 128;
    const int kb  = blockIdx.z * KS;
    const int bb  = bm0 / SEQ;
    const int t0  = bm0 - bb * SEQ;
    const int tx = tid & 15;
    const int ty = tid >> 4;
    const int arow = tid >> 5;
    const int am4  = (tid & 31) * 4;
    const int lrow = tid >> 1;
    const int lk4  = (tid & 1) * 4;
    float* C = Cpart + (size_t)blockIdx.z * MROWS * ldC;

    float acc[8][8];
#pragma unroll
    for (int i = 0; i < 8; i++)
#pragma unroll
        for (int j = 0; j < 8; j++) acc[i][j] = 0.f;

    for (int k0 = kb; k0 < kb + KS; k0 += 8) {
        const float4 av = *(const float4*)(AT + ((size_t)(bb * K + k0 + arow)) * SEQ + t0 + am4);
        float4 wv;
        const int wrow = bn0 + lrow;
        if (wrow < N) wv = *(const float4*)(W + (size_t)wrow * K + (k0 + lk4));
        else          wv = make_float4(0.f, 0.f, 0.f, 0.f);
        __syncthreads();
        *(float4*)&As[arow][am4] = av;
        Bs[lk4 + 0][lrow] = wv.x; Bs[lk4 + 1][lrow] = wv.y;
        Bs[lk4 + 2][lrow] = wv.z; Bs[lk4 + 3][lrow] = wv.w;
        __syncthreads();
#pragma unroll
        for (int kk = 0; kk < 8; kk++) {
            const float4 a0 = *(const float4*)&As[kk][ty * 8];
            const float4 a1 = *(const float4*)&As[kk][ty * 8 + 4];
            const float4 b0 = *(const float4*)&Bs[kk][tx * 8];
            const float4 b1 = *(const float4*)&Bs[kk][tx * 8 + 4];
            const float ar[8] = {a0.x, a0.y, a0.z, a0.w, a1.x, a1.y, a1.z, a1.w};
            const float br[8] = {b0.x, b0.y, b0.z, b0.w, b1.x, b1.y, b1.z, b1.w};
#pragma unroll
            for (int i = 0; i < 8; i++)
#pragma unroll
                for (int j = 0; j < 8; j++)
                    acc[i][j] = fmaf(ar[i], br[j], acc[i][j]);
        }
    }

#pragma unroll
    for (int i = 0; i < 8; i++) {
        const int row = bm0 + ty * 8 + i;
#pragma unroll
        for (int j4 = 0; j4 < 8; j4 += 4) {
            const int col = bn0 + tx * 8 + j4;
            if (col + 3 < N) {
                *(float4*)(C + (size_t)row * ldC + col) =
                    make_float4(acc[i][j4], acc[i][j4 + 1], acc[i][j4 + 2], acc[i][j4 + 3]);
            }
        }
    }
}

// Sum the 4 split-K partials into xdbl.
__global__ __launch_bounds__(256) void reduce4(
    const float* __restrict__ parts, float* __restrict__ out)
{
    const size_t i = ((size_t)blockIdx.x * 256 + threadIdx.x) * 4;
    const size_t S = (size_t)MROWS * XDC;
    float4 a = *(const float4*)(parts + i);
    const float4 b = *(const float4*)(parts + S + i);
    const float4 c = *(const float4*)(parts + 2 * S + i);
    const float4 d = *(const float4*)(parts + 3 * S + i);
    a.x += b.x + c.x + d.x;  a.y += b.y + c.y + d.y;
    a.z += b.z + c.z + d.z;  a.w += b.w + c.w + d.w;
    *(float4*)(out + i) = a;
}

// dt GEMM (small K=48): C = softplus(A[:, :48] @ W^T + bias), row-major.
__global__ __launch_bounds__(256, 2) void gemm_dt(
    const float* __restrict__ A, int ldA,
    const float* __restrict__ W,
    const float* __restrict__ bias,
    float* __restrict__ C, int ldC,
    int N, int K)
{
    __shared__ float As[8][132];
    __shared__ float Bs[8][132];
    const int tid = threadIdx.x;
    const int bm0 = blockIdx.y * 128;
    const int bn0 = blockIdx.x * 128;
    const int tx = tid & 15;
    const int ty = tid >> 4;
    const int lrow = tid >> 1;
    const int lk4  = (tid & 1) * 4;

    float acc[8][8];
#pragma unroll
    for (int i = 0; i < 8; i++)
#pragma unroll
        for (int j = 0; j < 8; j++) acc[i][j] = 0.f;

    for (int k0 = 0; k0 < K; k0 += 8) {
        const float4 av = *(const float4*)(A + (size_t)(bm0 + lrow) * ldA + (k0 + lk4));
        float4 wv;
        const int wrow = bn0 + lrow;
        if (wrow < N) wv = *(const float4*)(W + (size_t)wrow * K + (k0 + lk4));
        else          wv = make_float4(0.f, 0.f, 0.f, 0.f);
        __syncthreads();
        As[lk4 + 0][lrow] = av.x; As[lk4 + 1][lrow] = av.y;
        As[lk4 + 2][lrow] = av.z; As[lk4 + 3][lrow] = av.w;
        Bs[lk4 + 0][lrow] = wv.x; Bs[lk4 + 1][lrow] = wv.y;
        Bs[lk4 + 2][lrow] = wv.z; Bs[lk4 + 3][lrow] = wv.w;
        __syncthreads();
#pragma unroll
        for (int kk = 0; kk < 8; kk++) {
            const float4 a0 = *(const float4*)&As[kk][ty * 8];
            const float4 a1 = *(const float4*)&As[kk][ty * 8 + 4];
            const float4 b0 = *(const float4*)&Bs[kk][tx * 8];
            const float4 b1 = *(const float4*)&Bs[kk][tx * 8 + 4];
            const float ar[8] = {a0.x, a0.y, a0.z, a0.w, a1.x, a1.y, a1.z, a1.w};
            const float br[8] = {b0.x, b0.y, b0.z, b0.w, b1.x, b1.y, b1.z, b1.w};
#pragma unroll
            for (int i = 0; i < 8; i++)
#pragma unroll
                for (int j = 0; j < 8; j++)
                    acc[i][j] = fmaf(ar[i], br[j], acc[i][j]);
        }
    }

#pragma unroll
    for (int i = 0; i < 8; i++) {
        const int row = bm0 + ty * 8 + i;
#pragma unroll
        for (int j4 = 0; j4 < 8; j4 += 4) {
            const int col = bn0 + tx * 8 + j4;
            if (col + 3 < N) {
                float4 v = make_float4(acc[i][j4], acc[i][j4 + 1], acc[i][j4 + 2], acc[i][j4 + 3]);
                v.x = softplus_acc(v.x + bias[col + 0]);
                v.y = softplus_acc(v.y + bias[col + 1]);
                v.z = softplus_acc(v.z + bias[col + 2]);
                v.w = softplus_acc(v.w + bias[col + 3]);
                *(float4*)(C + (size_t)row * ldC + col) = v;
            }
        }
    }
}

// Depthwise causal conv (K=4) + SiLU -> uT [b][d][t] only.
__global__ __launch_bounds__(256) void conv_silu_T(
    const float* __restrict__ xz, const float* __restrict__ cw,
    const float* __restrict__ cb, float* __restrict__ uT)
{
    __shared__ float tin[67][65];
    __shared__ float ttr[64][65];
    const int tid = threadIdx.x;
    const int d0 = blockIdx.x * 64, t0 = blockIdx.y * 64, b = blockIdx.z;
    const int cl = tid & 63, q = tid >> 6;

    for (int r = q; r < 67; r += 4) {
        const int t = t0 - 3 + r;
        float v = 0.f;
        if (t >= 0) v = xz[((size_t)b * SEQ + t) * (2 * DI) + d0 + cl];
        tin[r][cl] = v;
    }
    __syncthreads();

    const float4 w = ((const float4*)cw)[d0 + cl];
    const float bb = cb[d0 + cl];
#pragma unroll
    for (int i = 0; i < 16; i++) {
        const int t = q * 16 + i;
        float a = bb;
        a = fmaf(tin[t + 0][cl], w.x, a);
        a = fmaf(tin[t + 1][cl], w.y, a);
        a = fmaf(tin[t + 2][cl], w.z, a);
        a = fmaf(tin[t + 3][cl], w.w, a);
        ttr[cl][t] = silu_fast(a);
    }
    __syncthreads();
#pragma unroll
    for (int i = 0; i < 16; i++) {
        const int d = q * 16 + i;
        uT[((size_t)b * DI + d0 + d) * SEQ + t0 + cl] = ttr[d][cl];
    }
}

// Tiled transpose: in[row=b*SEQ+t, coloff+c] (ld ldin) -> out[(b*ncols+c)*SEQ + t]
__global__ __launch_bounds__(256) void trans_r2t(
    const float* __restrict__ in, int ldin, int coloff,
    float* __restrict__ out, int ncols)
{
    __shared__ float tile[64][65];
    const int tid = threadIdx.x;
    const int c0 = blockIdx.x * 64, t0 = blockIdx.y * 64, b = blockIdx.z;
    const int cl = tid & 63, q = tid >> 6;
#pragma unroll
    for (int i = 0; i < 16; i++) {
        const int r = q * 16 + i;
        tile[r][cl] = in[((size_t)b * SEQ + t0 + r) * ldin + coloff + c0 + cl];
    }
    __syncthreads();
#pragma unroll
    for (int i = 0; i < 16; i++) {
        const int cc = q * 16 + i;
        out[((size_t)b * ncols + c0 + cc) * SEQ + t0 + cl] = tile[cl][cc];
    }
}

// B/C transpose into lane-interleaved layout:
//   bc4[(b*(SEQ/4) + t/4)*128 + ch] = float4{ x[t..t+3][ch] }
__global__ __launch_bounds__(256) void trans_bc_i4(
    const float* __restrict__ in, float4* __restrict__ bc4)
{
    __shared__ float tile[64][65];
    const int tid = threadIdx.x;
    const int c0 = blockIdx.x * 64, t0 = blockIdx.y * 64, b = blockIdx.z;
    const int cl = tid & 63, q = tid >> 6;
#pragma unroll
    for (int i = 0; i < 16; i++) {
        const int r = q * 16 + i;
        tile[r][cl] = in[((size_t)b * SEQ + t0 + r) * XDC + DTR + c0 + cl];
    }
    __syncthreads();
#pragma unroll
    for (int i = 0; i < 4; i++) {
        const int j = q * 4 + i;
        const float4 v = make_float4(tile[4 * j + 0][cl], tile[4 * j + 1][cl],
                                     tile[4 * j + 2][cl], tile[4 * j + 3][cl]);
        bc4[((size_t)b * (SEQ / 4) + (t0 / 4 + j)) * 128 + c0 + cl] = v;
    }
}

// ---------------- Chunked selective scan ----------------
// s output lives in the dead xz x-half via the linear map
//   addr(L) = (L/1536)*3072 + L%1536,  L = bd*SEQ + t.
// Every 256-t chunk starts at L % 256 == 0 and 1536 = 6*256, so each wave's
// span is contiguous.  All pointers honestly __restrict__ -> SMEM-eligible
// wave-uniform dt/u loads and free reordering.  Double-buffered, no guard:
// the final prefetch overreads <=64B into adjacent workspace (safe).

#define LOAD3(DT, UU, BB_, TB)                                         \
    _Pragma("unroll")                                                  \
    for (int g = 0; g < 4; g++) {                                      \
        DT[g]  = *(const float4*)(dtp + (TB) + 4 * g);                 \
        UU[g]  = *(const float4*)(up + (TB) + 4 * g);                  \
        BB_[g] = Bp[(size_t)((TB) / 4 + g) * 128];                     \
    }

#define LOAD4S(DT, UU, BB_, CC_, TB)                                   \
    _Pragma("unroll")                                                  \
    for (int g = 0; g < 4; g++) {                                      \
        DT[g]  = *(const float4*)(dtp + (TB) + 4 * g);                 \
        UU[g]  = *(const float4*)(up + (TB) + 4 * g);                  \
        BB_[g] = Bp[(size_t)((TB) / 4 + g) * 128];                     \
        CC_[g] = Cp[(size_t)((TB) / 4 + g) * 128];                     \
    }

#define P1_BLOCK(DT, UU, BB_)                                                                      \
    _Pragma("unroll")                                                                              \
    for (int g = 0; g < 4; g++) {                                                                  \
        h = fmaf(__builtin_amdgcn_exp2f(DT[g].x * An), h, (DT[g].x * UU[g].x) * BB_[g].x); sdt += DT[g].x; \
        h = fmaf(__builtin_amdgcn_exp2f(DT[g].y * An), h, (DT[g].y * UU[g].y) * BB_[g].y); sdt += DT[g].y; \
        h = fmaf(__builtin_amdgcn_exp2f(DT[g].z * An), h, (DT[g].z * UU[g].z) * BB_[g].z); sdt += DT[g].z; \
        h = fmaf(__builtin_amdgcn_exp2f(DT[g].w * An), h, (DT[g].w * UU[g].w) * BB_[g].w); sdt += DT[g].w; \
    }

#define P3_BLOCK(DT, UU, BB_, CC_, TBASE)                                                          \
    {                                                                                              \
        float p[16];                                                                               \
        _Pragma("unroll")                                                                          \
        for (int g = 0; g < 4; g++) {                                                              \
            h = fmaf(__builtin_amdgcn_exp2f(DT[g].x * An), h, (DT[g].x * UU[g].x) * BB_[g].x); p[4*g+0] = h * CC_[g].x; \
            h = fmaf(__builtin_amdgcn_exp2f(DT[g].y * An), h, (DT[g].y * UU[g].y) * BB_[g].y); p[4*g+1] = h * CC_[g].y; \
            h = fmaf(__builtin_amdgcn_exp2f(DT[g].z * An), h, (DT[g].z * UU[g].z) * BB_[g].z); p[4*g+2] = h * CC_[g].z; \
            h = fmaf(__builtin_amdgcn_exp2f(DT[g].w * An), h, (DT[g].w * UU[g].w) * BB_[g].w); p[4*g+3] = h * CC_[g].w; \
        }                                                                                          \
        _Pragma("unroll")                                                                          \
        for (int i = 0; i < 16; i++) slab[i * 65 + lane] = p[i];                                   \
        float s = 0.f;                                                                             \
        _Pragma("unroll")                                                                          \
        for (int j = 0; j < 16; j++) s += slab[tt * 65 + seg * 16 + j];                            \
        s += __shfl_xor(s, 16, 64);                                                                \
        s += __shfl_xor(s, 32, 64);                                                                \
        if (lane < 16) sp[(TBASE) + tt] = s;                                                       \
    }

__global__ __launch_bounds__(256, 2) void scan_phase1(
    const float* __restrict__ dtT, const float* __restrict__ uT,
    const float4* __restrict__ bc4, const float* __restrict__ A_log,
    float* __restrict__ hend, float* __restrict__ prodA)
{
    const int wid  = __builtin_amdgcn_readfirstlane(
                        (int)((blockIdx.x * 256 + threadIdx.x) >> 6));
    const int lane = threadIdx.x & 63;
    const int c  = wid & (NC - 1);
    const int bd = wid >> 3;
    const int b  = bd / DI;
    const int d  = bd - b * DI;

    const float An = -expf(A_log[d * DS + lane]) * LOG2E;
    const float* dtp = dtT + (size_t)bd * SEQ + c * TCH;
    const float* up  = uT  + (size_t)bd * SEQ + c * TCH;
    const float4* Bp = bc4 + ((size_t)b * (SEQ / 4) + c * (TCH / 4)) * 128 + lane;

    float4 dA4[4], uA4[4], BA4[4], dB4[4], uB4[4], BB4[4];
    LOAD3(dA4, uA4, BA4, 0);

    float h = 0.f, sdt = 0.f;
    for (int tb = 0; tb < TCH; tb += 32) {
        LOAD3(dB4, uB4, BB4, tb + 16);
        P1_BLOCK(dA4, uA4, BA4);
        LOAD3(dA4, uA4, BA4, tb + 32);     // final iter overreads (safe)
        P1_BLOCK(dB4, uB4, BB4);
    }
    hend [(size_t)wid * DS + lane] = h;
    prodA[(size_t)wid * DS + lane] = __builtin_amdgcn_exp2f(An * sdt);
}

__global__ __launch_bounds__(256) void scan_phase2(
    float* __restrict__ hend, float* __restrict__ prodA)
{
    const int bd   = (blockIdx.x * 256 + threadIdx.x) >> 6;
    const int lane = threadIdx.x & 63;
    float h = 0.f;
#pragma unroll
    for (int c = 0; c < NC; c++) {
        const size_t off = ((size_t)bd * NC + c) * DS + lane;
        const float pA = prodA[off];
        const float he = hend[off];
        prodA[off] = h;
        h = fmaf(pA, h, he);
    }
}

__global__ __launch_bounds__(256, 2) void scan_phase3(
    const float* __restrict__ dtT, const float* __restrict__ uT,
    const float4* __restrict__ bc4, const float* __restrict__ A_log,
    const float* __restrict__ hin, float* __restrict__ sX)
{
    __shared__ float red[4][16 * 65];
    const int wid  = __builtin_amdgcn_readfirstlane(
                        (int)((blockIdx.x * 256 + threadIdx.x) >> 6));
    const int lane = threadIdx.x & 63;
    const int c  = wid & (NC - 1);
    const int bd = wid >> 3;
    const int b  = bd / DI;
    const int d  = bd - b * DI;

    const float An = -expf(A_log[d * DS + lane]) * LOG2E;
    const float* dtp = dtT + (size_t)bd * SEQ + c * TCH;
    const float* up  = uT  + (size_t)bd * SEQ + c * TCH;
    const float4* Bp = bc4 + ((size_t)b * (SEQ / 4) + c * (TCH / 4)) * 128 + lane;
    const float4* Cp = Bp + 64;
    const size_t L0 = (size_t)bd * SEQ + c * TCH;
    float* sp = sX + (L0 / 1536) * 3072 + (L0 % 1536);
    float* slab = &red[threadIdx.x >> 6][0];
    const int tt = lane & 15, seg = lane >> 4;

    float4 dA4[4], uA4[4], BA4[4], CA4[4], dB4[4], uB4[4], BB4[4], CB4[4];
    LOAD4S(dA4, uA4, BA4, CA4, 0);

    float h = hin[(size_t)wid * DS + lane];
    for (int tb = 0; tb < TCH; tb += 32) {
        LOAD4S(dB4, uB4, BB4, CB4, tb + 16);
        P3_BLOCK(dA4, uA4, BA4, CA4, tb);
        LOAD4S(dA4, uA4, BA4, CA4, tb + 32);   // final iter overreads (safe)
        P3_BLOCK(dB4, uB4, BB4, CB4, tb + 16);
    }
}

// Gate: y = (s + D*u) * silu(z), written fp32 IN PLACE over uT (same-thread
// read-then-write; each element touched by exactly one thread -> race-free).
// s read from the mapped xz x-half; z read row-major via LDS tile.
__global__ __launch_bounds__(256) void gate_io(
    const float* __restrict__ xz,      // s (x-half, mapped) + z (z-half)
    float* uy,                          // in: u [bd][t]; out: y (same layout)
    const float* __restrict__ Dskip)
{
    __shared__ float zt[64][65];        // [t][d]
    const int tid = threadIdx.x;
    const int d0 = blockIdx.x * 64, t0 = blockIdx.y * 64, b = blockIdx.z;
    const int cl = tid & 63, q = tid >> 6;
#pragma unroll
    for (int i = 0; i < 16; i++) {
        const int r = q * 16 + i;
        zt[r][cl] = xz[((size_t)b * SEQ + t0 + r) * (2 * DI) + DI + d0 + cl];
    }
    __syncthreads();
#pragma unroll
    for (int i = 0; i < 16; i++) {
        const int dd = q * 16 + i;
        const size_t Lrow = ((size_t)b * DI + d0 + dd) * SEQ + t0;
        const float s = xz[(Lrow / 1536) * 3072 + (Lrow % 1536) + cl];
        const size_t uoff = Lrow + cl;
        const float u = uy[uoff];
        const float Dd = Dskip[d0 + dd];           // wave-uniform
        uy[uoff] = (s + Dd * u) * silu_fast(zt[cl][dd]);
    }
}

// Transpose + bf16-split y [bd][t] -> packed planes in the xz x-half:
//   yh(r,c) at ypk[r*6144 + c], yl(r,c) at ypk[r*6144 + 1536 + c]  (ushorts).
__global__ __launch_bounds__(256) void split_y_T(
    const float* __restrict__ yT, ushort_t* __restrict__ ypk)
{
    __shared__ float tile[64][65];      // [t][d]
    const int tid = threadIdx.x;
    const int d0 = blockIdx.x * 64, t0 = blockIdx.y * 64, b = blockIdx.z;
    const int cl = tid & 63, q = tid >> 6;
#pragma unroll
    for (int i = 0; i < 16; i++) {
        const int dd = q * 16 + i;
        tile[cl][dd] = yT[((size_t)b * DI + d0 + dd) * SEQ + t0 + cl];
    }
    __syncthreads();
#pragma unroll
    for (int i = 0; i < 16; i++) {
        const int t = q * 16 + i;
        const size_t row = (size_t)b * SEQ + t0 + t;
        ushort_t h, l;
        bf16_split(tile[t][cl], h, l);
        ypk[row * 6144 + d0 + cl] = h;
        ypk[row * 6144 + 1536 + d0 + cl] = l;
    }
}

extern "C" void kernel_launch(void* const* d_in, const int* in_sizes, int n_in,
                              void* d_out, int out_size, void* d_ws, size_t ws_size,
                              hipStream_t stream) {
    (void)in_sizes; (void)n_in; (void)out_size; (void)ws_size;
    const float* x    = (const float*)d_in[0];
    const float* Wi   = (const float*)d_in[1];
    const float* cw   = (const float*)d_in[2];
    const float* cb   = (const float*)d_in[3];
    const float* Wx   = (const float*)d_in[4];
    const float* Wdt  = (const float*)d_in[5];
    const float* bdt  = (const float*)d_in[6];
    const float* Alog = (const float*)d_in[7];
    const float* Dsk  = (const float*)d_in[8];
    const float* Wo   = (const float*)d_in[9];
    float* out = (float*)d_out;

    // Workspace (fp32), ~236 MB:
    float* xz    = (float*)d_ws;                          // [MROWS, 3072]; x-half: dt-rm -> s(mapped) -> ypk
    float* uT    = xz    + (size_t)MROWS * (2 * DI);      // [B*DI, SEQ]: sh/sl arena -> u -> y (gate in-place)
    float* dtT   = uT    + (size_t)MROWS * DI;            // [B*DI, SEQ]: wih/wil arena -> dt -> layer0 dst
    float* xdbl  = dtT   + (size_t)MROWS * DI;            // [MROWS, 176]; also woh/wol arena
    float* bcT   = xdbl  + (size_t)MROWS * XDC;           // [B][SEQ/4][128][4] interleaved
    float* xnext = bcT   + (size_t)BATCH * 128 * SEQ;     // scratch: split-K partials / hend+prodA
    float* parts = xnext;                                 // [4][MROWS, XDC]
    float* hend  = xnext;                                 // [B*DI*NC, DS]
    float* prodA = xnext + (size_t)BATCH * DI * NC * DS;  // [B*DI*NC, DS]

    // bf16 plane homes (disjoint lifetimes):
    ushort_t* sh  = (ushort_t*)uT;                        // [MROWS, DM] x2
    ushort_t* sl  = sh  + (size_t)MROWS * DM;
    ushort_t* wih = (ushort_t*)(dtT + (size_t)MROWS * DM);// above layer-0 dst region
    ushort_t* wil = wih + (size_t)2 * DI * DM;
    ushort_t* woh = (ushort_t*)xdbl;                      // [DM, DI] x2
    ushort_t* wol = woh + (size_t)DM * DI;
    ushort_t* ypk = (ushort_t*)xz;                        // packed y planes in xz x-half

    const float* src = x;
    for (int i = 0; i < DEPTH; i++) {
        const float* Wi_l   = Wi   + (size_t)i * 2 * DI * DM;
        const float* cw_l   = cw   + (size_t)i * DI * DC;
        const float* cb_l   = cb   + (size_t)i * DI;
        const float* Wx_l   = Wx   + (size_t)i * XDC * DI;
        const float* Wdt_l  = Wdt  + (size_t)i * DI * DTR;
        const float* bdt_l  = bdt  + (size_t)i * DI;
        const float* Alog_l = Alog + (size_t)i * DI * DS;
        const float* Dsk_l  = Dsk  + (size_t)i * DI;
        const float* Wo_l   = Wo   + (size_t)i * DM * DI;
        float* dst = (i == DEPTH - 1) ? out : dtT;        // layer-0 dst in dtT region

        // 1. split src and Wi to bf16 hi/lo planes
        split_bf16<<<(size_t)MROWS * DM / 1024, 256, 0, stream>>>(src, sh, sl);
        split_bf16<<<(size_t)2 * DI * DM / 1024, 256, 0, stream>>>(Wi_l, wih, wil);
        // 2. xz = src @ Wi^T  (bf16x2 MFMA)        [8192, 3072]
        gemm_mfma<<<dim3(2 * DI / 128, MROWS / 128), 256, 0, stream>>>(
            sh, sl, wih, wil, xz, 2 * DI, DM, DM, DM);
        // 3. uT = silu(conv(xz[:, :DI])) transposed [b][d][t]
        conv_silu_T<<<dim3(DI / 64, SEQ / 64, BATCH), 256, 0, stream>>>(
            xz, cw_l, cb_l, uT);
        // 4. xdbl = u @ Wx^T via k-major uT, split-K=4 -> partials, reduce
        gemm_tn_sk<<<dim3((XDC + 127) / 128, MROWS / 128, 4), 256, 0, stream>>>(
            uT, Wx_l, parts, XDC, XDC, DI, DI / 4);
        reduce4<<<(size_t)MROWS * XDC / 1024, 256, 0, stream>>>(parts, xdbl);
        // 5. B/C -> lane-interleaved bc4 layout
        trans_bc_i4<<<dim3(2, SEQ / 64, BATCH), 256, 0, stream>>>(
            xdbl, (float4*)bcT);
        // 6. dt = softplus(xdbl[:, :48] @ Wdt^T + bdt) -> xz[:, 0:DI]
        gemm_dt<<<dim3(DI / 128, MROWS / 128), 256, 0, stream>>>(
            xdbl, XDC, Wdt_l, bdt_l, xz, 2 * DI, DI, DTR);
        // 7. dt transpose -> dtT [b][d][t]  (dt row-major in xz now dead)
        trans_r2t<<<dim3(DI / 64, SEQ / 64, BATCH), 256, 0, stream>>>(
            xz, 2 * DI, 0, dtT, DI);
        // 8-10. chunked scan; phase3 writes s into xz x-half (mapped)
        scan_phase1<<<(BATCH * DI * NC) / 4, 256, 0, stream>>>(
            dtT, uT, (const float4*)bcT, Alog_l, hend, prodA);
        scan_phase2<<<(BATCH * DI) / 4, 256, 0, stream>>>(hend, prodA);
        scan_phase3<<<(BATCH * DI * NC) / 4, 256, 0, stream>>>(
            dtT, uT, (const float4*)bcT, Alog_l, prodA, xz);
        // 11. gate: y fp32 in place over uT
        gate_io<<<dim3(DI / 64, SEQ / 64, BATCH), 256, 0, stream>>>(
            xz, uT, Dsk_l);
        // 12. transpose + split y -> packed planes in xz x-half (s dead)
        split_y_T<<<dim3(DI / 64, SEQ / 64, BATCH), 256, 0, stream>>>(uT, ypk);
        // 13. split Wo planes (xdbl region, dead)
        split_bf16<<<(size_t)DM * DI / 1024, 256, 0, stream>>>(Wo_l, woh, wol);
        // 14. dst = y @ Wo^T  (bf16x2 MFMA, packed-A layout)
        gemm_mfma<<<dim3(DM / 128, MROWS / 128), 256, 0, stream>>>(
            ypk, ypk + 1536, woh, wol, dst, DM, DI, 6144, DI);

        src = dst;
    }
}

// Round 11
// 1750.867 us; speedup vs baseline: 1.4352x; 1.0464x over previous
//
#include <hip/hip_runtime.h>
#include <hip/hip_bf16.h>
#include <math.h>

// Problem constants (MambaStack reference)
#define DEPTH   2
#define DM      768      // d_model
#define DS      64       // d_state
#define DC      4        // d_conv
#define DI      1536     // d_inner
#define DTR     48       // dt_rank
#define BATCH   4
#define SEQ     2048
#define MROWS   (BATCH*SEQ)          // 8192
#define XDC     (DTR + 2*DS)         // 176 (xdbl cols)
#define NC      8                    // scan chunks
#define TCH     (SEQ/NC)             // 256 timesteps per chunk
#define LOG2E   1.44269504088896f

typedef __attribute__((ext_vector_type(8))) short bf16x8;
typedef __attribute__((ext_vector_type(4))) float f32x4;
typedef unsigned short ushort_t;
#define GAS __attribute__((address_space(1)))
#define LAS __attribute__((address_space(3)))

__device__ __forceinline__ float silu_fast(float x) {
    return x / (1.f + __expf(-x));
}
__device__ __forceinline__ float softplus_acc(float x) {
    return x > 20.f ? x : log1pf(expf(x));
}

// Split fp32 -> (hi, lo) bf16 pair, both RNE.  hi+lo represents f to ~2^-17.
__device__ __forceinline__ void bf16_split(float f, ushort_t& h, ushort_t& l) {
    unsigned u = __float_as_uint(f);
    unsigned hr = u + 0x7FFF + ((u >> 16) & 1);
    h = (ushort_t)(hr >> 16);
    float lof = f - __uint_as_float((unsigned)h << 16);
    unsigned ul = __float_as_uint(lof);
    unsigned lr = ul + 0x7FFF + ((ul >> 16) & 1);
    l = (ushort_t)(lr >> 16);
}

// Contiguous fp32 array -> hi/lo bf16 planes.  n multiple of 1024.
__global__ __launch_bounds__(256) void split_bf16(
    const float* __restrict__ in, ushort_t* __restrict__ hi,
    ushort_t* __restrict__ lo)
{
    const size_t i = ((size_t)blockIdx.x * 256 + threadIdx.x) * 4;
    const float4 v = *(const float4*)(in + i);
    ushort4 h, l;
    bf16_split(v.x, h.x, l.x); bf16_split(v.y, h.y, l.y);
    bf16_split(v.z, h.z, l.z); bf16_split(v.w, h.w, l.w);
    *(ushort4*)(hi + i) = h;
    *(ushort4*)(lo + i) = l;
}

// ---------------- bf16x2-split MFMA GEMM ----------------
// C[M,N] = (Ah+Al) @ (Wh+Wl)^T, planes bf16, row strides ldA/ldW (elements).
// 128x128 tile, BK=32, 4 waves; 16x16x32 MFMA, 3 per tile (hh, hl, lh).
// If Chi != null, the output is emitted as bf16 hi/lo planes instead of fp32.
// N-guard on the fp32 store path (used with N=176 for x_proj).
__global__ __launch_bounds__(256, 2) void gemm_mfma(
    const ushort_t* __restrict__ Ah, const ushort_t* __restrict__ Al,
    const ushort_t* __restrict__ Wh, const ushort_t* __restrict__ Wl,
    float* __restrict__ C, int N, int K, int ldA, int ldW,
    ushort_t* __restrict__ Chi, ushort_t* __restrict__ Clo)
{
    __shared__ ushort_t lds[4][128 * 32];
    const int tid  = threadIdx.x;
    const int wave = tid >> 6, lane = tid & 63;
    const int bm0 = blockIdx.y * 128, bn0 = blockIdx.x * 128;
    const int wm = (wave >> 1) * 64, wn = (wave & 1) * 64;

    const ushort_t* gp = (wave == 0) ? Ah : (wave == 1) ? Al : (wave == 2) ? Wh : Wl;
    const int ldg = (wave < 2) ? ldA : ldW;
    const int rb = (wave < 2) ? bm0 : bn0;
    const int srow = lane >> 2;           // 0..15
    const int skq  = (lane & 3) * 8;      // k offset in elements

    f32x4 acc[4][4];
#pragma unroll
    for (int i = 0; i < 4; i++)
#pragma unroll
        for (int j = 0; j < 4; j++) acc[i][j] = (f32x4){0.f, 0.f, 0.f, 0.f};

    const int lm  = lane & 15;
    const int kg8 = (lane >> 4) * 8;

    for (int k0 = 0; k0 < K; k0 += 32) {
#pragma unroll
        for (int j = 0; j < 8; j++) {
            const ushort_t* ga = gp + (size_t)(rb + j * 16 + srow) * ldg + k0 + skq;
            __builtin_amdgcn_global_load_lds(
                (const GAS unsigned*)ga, (LAS unsigned*)&lds[wave][j * 512], 16, 0, 0);
        }
        __syncthreads();

        bf16x8 ah[4], al[4], bh[4], bl[4];
#pragma unroll
        for (int i = 0; i < 4; i++) {
            const int ar = (wm + i * 16 + lm) * 32 + kg8;
            ah[i] = *(const bf16x8*)&lds[0][ar];
            al[i] = *(const bf16x8*)&lds[1][ar];
            const int br = (wn + i * 16 + lm) * 32 + kg8;
            bh[i] = *(const bf16x8*)&lds[2][br];
            bl[i] = *(const bf16x8*)&lds[3][br];
        }
#pragma unroll
        for (int mi = 0; mi < 4; mi++)
#pragma unroll
            for (int ni = 0; ni < 4; ni++) {
                f32x4 t = acc[mi][ni];
                t = __builtin_amdgcn_mfma_f32_16x16x32_bf16(al[mi], bh[ni], t, 0, 0, 0);
                t = __builtin_amdgcn_mfma_f32_16x16x32_bf16(ah[mi], bl[ni], t, 0, 0, 0);
                t = __builtin_amdgcn_mfma_f32_16x16x32_bf16(ah[mi], bh[ni], t, 0, 0, 0);
                acc[mi][ni] = t;
            }
        __syncthreads();
    }

#pragma unroll
    for (int mi = 0; mi < 4; mi++)
#pragma unroll
        for (int ni = 0; ni < 4; ni++)
#pragma unroll
            for (int r = 0; r < 4; r++) {
                const int rowg = bm0 + wm + mi * 16 + (lane >> 4) * 4 + r;
                const int colg = bn0 + wn + ni * 16 + lm;
                const float v = acc[mi][ni][r];
                if (Chi) {
                    ushort_t h, l;
                    bf16_split(v, h, l);
                    Chi[(size_t)rowg * N + colg] = h;
                    Clo[(size_t)rowg * N + colg] = l;
                } else if (colg < N) {
                    C[(size_t)rowg * N + colg] = v;
                }
            }
}

// dt GEMM, transposed output: dtT[(b*DI+d)*SEQ + t] =
//   softplus(sum_k Wdt[d][k] * xdbl[b*SEQ+t][k] + bias[d]).
// An NT GEMM with M-dim = d (rows of Wdt), N-dim = t (rows of xdbl), K=48.
// Grid (SEQ/128, DI/128, BATCH).  Fully coalesced stores; kills trans_r2t.
__global__ __launch_bounds__(256, 2) void gemm_dt_T(
    const float* __restrict__ Wdt, const float* __restrict__ xdbl,
    const float* __restrict__ bias, float* __restrict__ dtT)
{
    __shared__ float As[8][132];
    __shared__ float Bs[8][132];
    const int tid = threadIdx.x;
    const int bd0 = blockIdx.y * 128;   // d tile
    const int bt0 = blockIdx.x * 128;   // t tile
    const int b   = blockIdx.z;
    const int tx = tid & 15;            // t group
    const int ty = tid >> 4;            // d group
    const int lrow = tid >> 1;
    const int lk4  = (tid & 1) * 4;

    float acc[8][8];
#pragma unroll
    for (int i = 0; i < 8; i++)
#pragma unroll
        for (int j = 0; j < 8; j++) acc[i][j] = 0.f;

    for (int k0 = 0; k0 < DTR; k0 += 8) {
        const float4 av = *(const float4*)(Wdt + (size_t)(bd0 + lrow) * DTR + k0 + lk4);
        const float4 wv = *(const float4*)(xdbl + ((size_t)b * SEQ + bt0 + lrow) * XDC + k0 + lk4);
        __syncthreads();
        As[lk4 + 0][lrow] = av.x; As[lk4 + 1][lrow] = av.y;
        As[lk4 + 2][lrow] = av.z; As[lk4 + 3][lrow] = av.w;
        Bs[lk4 + 0][lrow] = wv.x; Bs[lk4 + 1][lrow] = wv.y;
        Bs[lk4 + 2][lrow] = wv.z; Bs[lk4 + 3][lrow] = wv.w;
        __syncthreads();
#pragma unroll
        for (int kk = 0; kk < 8; kk++) {
            const float4 a0 = *(const float4*)&As[kk][ty * 8];
            const float4 a1 = *(const float4*)&As[kk][ty * 8 + 4];
            const float4 b0 = *(const float4*)&Bs[kk][tx * 8];
            const float4 b1 = *(const float4*)&Bs[kk][tx * 8 + 4];
            const float ar[8] = {a0.x, a0.y, a0.z, a0.w, a1.x, a1.y, a1.z, a1.w};
            const float br[8] = {b0.x, b0.y, b0.z, b0.w, b1.x, b1.y, b1.z, b1.w};
#pragma unroll
            for (int i = 0; i < 8; i++)
#pragma unroll
                for (int j = 0; j < 8; j++)
                    acc[i][j] = fmaf(ar[i], br[j], acc[i][j]);
        }
    }

#pragma unroll
    for (int i = 0; i < 8; i++) {
        const int d = bd0 + ty * 8 + i;
        const float bb = bias[d];
#pragma unroll
        for (int j4 = 0; j4 < 8; j4 += 4) {
            float4 v = make_float4(acc[i][j4], acc[i][j4 + 1], acc[i][j4 + 2], acc[i][j4 + 3]);
            v.x = softplus_acc(v.x + bb);
            v.y = softplus_acc(v.y + bb);
            v.z = softplus_acc(v.z + bb);
            v.w = softplus_acc(v.w + bb);
            *(float4*)(dtT + ((size_t)b * DI + d) * SEQ + bt0 + tx * 8 + j4) = v;
        }
    }
}

// Depthwise causal conv (K=4) + SiLU -> uT [b][d][t] fp32 AND row-major
// bf16 hi/lo planes (for the x_proj MFMA GEMM).
__global__ __launch_bounds__(256) void conv_silu_T2(
    const float* __restrict__ xz, const float* __restrict__ cw,
    const float* __restrict__ cb, float* __restrict__ uT,
    ushort_t* __restrict__ uh, ushort_t* __restrict__ ul)
{
    __shared__ float tin[67][65];
    __shared__ float ttr[64][65];
    const int tid = threadIdx.x;
    const int d0 = blockIdx.x * 64, t0 = blockIdx.y * 64, b = blockIdx.z;
    const int cl = tid & 63, q = tid >> 6;

    for (int r = q; r < 67; r += 4) {
        const int t = t0 - 3 + r;
        float v = 0.f;
        if (t >= 0) v = xz[((size_t)b * SEQ + t) * (2 * DI) + d0 + cl];
        tin[r][cl] = v;
    }
    __syncthreads();

    const float4 w = ((const float4*)cw)[d0 + cl];
    const float bb = cb[d0 + cl];
#pragma unroll
    for (int i = 0; i < 16; i++) {
        const int t = q * 16 + i;
        float a = bb;
        a = fmaf(tin[t + 0][cl], w.x, a);
        a = fmaf(tin[t + 1][cl], w.y, a);
        a = fmaf(tin[t + 2][cl], w.z, a);
        a = fmaf(tin[t + 3][cl], w.w, a);
        a = silu_fast(a);
        ttr[cl][t] = a;
        ushort_t h, l;
        bf16_split(a, h, l);
        const size_t row = (size_t)b * SEQ + t0 + t;
        uh[row * DI + d0 + cl] = h;          // coalesced in d
        ul[row * DI + d0 + cl] = l;
    }
    __syncthreads();
#pragma unroll
    for (int i = 0; i < 16; i++) {
        const int d = q * 16 + i;
        uT[((size_t)b * DI + d0 + d) * SEQ + t0 + cl] = ttr[d][cl];  // coalesced in t
    }
}

// B/C transpose into lane-interleaved layout:
//   bc4[(b*(SEQ/4) + t/4)*128 + ch] = float4{ x[t..t+3][ch] }
__global__ __launch_bounds__(256) void trans_bc_i4(
    const float* __restrict__ in, float4* __restrict__ bc4)
{
    __shared__ float tile[64][65];
    const int tid = threadIdx.x;
    const int c0 = blockIdx.x * 64, t0 = blockIdx.y * 64, b = blockIdx.z;
    const int cl = tid & 63, q = tid >> 6;
#pragma unroll
    for (int i = 0; i < 16; i++) {
        const int r = q * 16 + i;
        tile[r][cl] = in[((size_t)b * SEQ + t0 + r) * XDC + DTR + c0 + cl];
    }
    __syncthreads();
#pragma unroll
    for (int i = 0; i < 4; i++) {
        const int j = q * 4 + i;
        const float4 v = make_float4(tile[4 * j + 0][cl], tile[4 * j + 1][cl],
                                     tile[4 * j + 2][cl], tile[4 * j + 3][cl]);
        bc4[((size_t)b * (SEQ / 4) + (t0 / 4 + j)) * 128 + c0 + cl] = v;
    }
}

// ---------------- Chunked selective scan ----------------
// s output lives in the dead xz x-half via the linear map
//   addr(L) = (L/1536)*3072 + L%1536,  L = bd*SEQ + t.
// All pointers honestly __restrict__; double-buffered, no guard (final
// prefetch overreads <=64B into adjacent workspace, safe).

#define LOAD3(DT, UU, BB_, TB)                                         \
    _Pragma("unroll")                                                  \
    for (int g = 0; g < 4; g++) {                                      \
        DT[g]  = *(const float4*)(dtp + (TB) + 4 * g);                 \
        UU[g]  = *(const float4*)(up + (TB) + 4 * g);                  \
        BB_[g] = Bp[(size_t)((TB) / 4 + g) * 128];                     \
    }

#define LOAD4S(DT, UU, BB_, CC_, TB)                                   \
    _Pragma("unroll")                                                  \
    for (int g = 0; g < 4; g++) {                                      \
        DT[g]  = *(const float4*)(dtp + (TB) + 4 * g);                 \
        UU[g]  = *(const float4*)(up + (TB) + 4 * g);                  \
        BB_[g] = Bp[(size_t)((TB) / 4 + g) * 128];                     \
        CC_[g] = Cp[(size_t)((TB) / 4 + g) * 128];                     \
    }

#define P1_BLOCK(DT, UU, BB_)                                                                      \
    _Pragma("unroll")                                                                              \
    for (int g = 0; g < 4; g++) {                                                                  \
        h = fmaf(__builtin_amdgcn_exp2f(DT[g].x * An), h, (DT[g].x * UU[g].x) * BB_[g].x); sdt += DT[g].x; \
        h = fmaf(__builtin_amdgcn_exp2f(DT[g].y * An), h, (DT[g].y * UU[g].y) * BB_[g].y); sdt += DT[g].y; \
        h = fmaf(__builtin_amdgcn_exp2f(DT[g].z * An), h, (DT[g].z * UU[g].z) * BB_[g].z); sdt += DT[g].z; \
        h = fmaf(__builtin_amdgcn_exp2f(DT[g].w * An), h, (DT[g].w * UU[g].w) * BB_[g].w); sdt += DT[g].w; \
    }

#define P3_BLOCK(DT, UU, BB_, CC_, TBASE)                                                          \
    {                                                                                              \
        float p[16];                                                                               \
        _Pragma("unroll")                                                                          \
        for (int g = 0; g < 4; g++) {                                                              \
            h = fmaf(__builtin_amdgcn_exp2f(DT[g].x * An), h, (DT[g].x * UU[g].x) * BB_[g].x); p[4*g+0] = h * CC_[g].x; \
            h = fmaf(__builtin_amdgcn_exp2f(DT[g].y * An), h, (DT[g].y * UU[g].y) * BB_[g].y); p[4*g+1] = h * CC_[g].y; \
            h = fmaf(__builtin_amdgcn_exp2f(DT[g].z * An), h, (DT[g].z * UU[g].z) * BB_[g].z); p[4*g+2] = h * CC_[g].z; \
            h = fmaf(__builtin_amdgcn_exp2f(DT[g].w * An), h, (DT[g].w * UU[g].w) * BB_[g].w); p[4*g+3] = h * CC_[g].w; \
        }                                                                                          \
        _Pragma("unroll")                                                                          \
        for (int i = 0; i < 16; i++) slab[i * 65 + lane] = p[i];                                   \
        float s = 0.f;                                                                             \
        _Pragma("unroll")                                                                          \
        for (int j = 0; j < 16; j++) s += slab[tt * 65 + seg * 16 + j];                            \
        s += __shfl_xor(s, 16, 64);                                                                \
        s += __shfl_xor(s, 32, 64);                                                                \
        if (lane < 16) sp[(TBASE) + tt] = s;                                                       \
    }

__global__ __launch_bounds__(256, 2) void scan_phase1(
    const float* __restrict__ dtT, const float* __restrict__ uT,
    const float4* __restrict__ bc4, const float* __restrict__ A_log,
    float* __restrict__ hend, float* __restrict__ prodA)
{
    const int wid  = __builtin_amdgcn_readfirstlane(
                        (int)((blockIdx.x * 256 + threadIdx.x) >> 6));
    const int lane = threadIdx.x & 63;
    const int c  = wid & (NC - 1);
    const int bd = wid >> 3;
    const int b  = bd / DI;
    const int d  = bd - b * DI;

    const float An = -expf(A_log[d * DS + lane]) * LOG2E;
    const float* dtp = dtT + (size_t)bd * SEQ + c * TCH;
    const float* up  = uT  + (size_t)bd * SEQ + c * TCH;
    const float4* Bp = bc4 + ((size_t)b * (SEQ / 4) + c * (TCH / 4)) * 128 + lane;

    float4 dA4[4], uA4[4], BA4[4], dB4[4], uB4[4], BB4[4];
    LOAD3(dA4, uA4, BA4, 0);

    float h = 0.f, sdt = 0.f;
    for (int tb = 0; tb < TCH; tb += 32) {
        LOAD3(dB4, uB4, BB4, tb + 16);
        P1_BLOCK(dA4, uA4, BA4);
        LOAD3(dA4, uA4, BA4, tb + 32);     // final iter overreads (safe)
        P1_BLOCK(dB4, uB4, BB4);
    }
    hend [(size_t)wid * DS + lane] = h;
    prodA[(size_t)wid * DS + lane] = __builtin_amdgcn_exp2f(An * sdt);
}

__global__ __launch_bounds__(256) void scan_phase2(
    float* __restrict__ hend, float* __restrict__ prodA)
{
    const int bd   = (blockIdx.x * 256 + threadIdx.x) >> 6;
    const int lane = threadIdx.x & 63;
    float h = 0.f;
#pragma unroll
    for (int c = 0; c < NC; c++) {
        const size_t off = ((size_t)bd * NC + c) * DS + lane;
        const float pA = prodA[off];
        const float he = hend[off];
        prodA[off] = h;
        h = fmaf(pA, h, he);
    }
}

__global__ __launch_bounds__(256, 2) void scan_phase3(
    const float* __restrict__ dtT, const float* __restrict__ uT,
    const float4* __restrict__ bc4, const float* __restrict__ A_log,
    const float* __restrict__ hin, float* __restrict__ sX)
{
    __shared__ float red[4][16 * 65];
    const int wid  = __builtin_amdgcn_readfirstlane(
                        (int)((blockIdx.x * 256 + threadIdx.x) >> 6));
    const int lane = threadIdx.x & 63;
    const int c  = wid & (NC - 1);
    const int bd = wid >> 3;
    const int b  = bd / DI;
    const int d  = bd - b * DI;

    const float An = -expf(A_log[d * DS + lane]) * LOG2E;
    const float* dtp = dtT + (size_t)bd * SEQ + c * TCH;
    const float* up  = uT  + (size_t)bd * SEQ + c * TCH;
    const float4* Bp = bc4 + ((size_t)b * (SEQ / 4) + c * (TCH / 4)) * 128 + lane;
    const float4* Cp = Bp + 64;
    const size_t L0 = (size_t)bd * SEQ + c * TCH;
    float* sp = sX + (L0 / 1536) * 3072 + (L0 % 1536);
    float* slab = &red[threadIdx.x >> 6][0];
    const int tt = lane & 15, seg = lane >> 4;

    float4 dA4[4], uA4[4], BA4[4], CA4[4], dB4[4], uB4[4], BB4[4], CB4[4];
    LOAD4S(dA4, uA4, BA4, CA4, 0);

    float h = hin[(size_t)wid * DS + lane];
    for (int tb = 0; tb < TCH; tb += 32) {
        LOAD4S(dB4, uB4, BB4, CB4, tb + 16);
        P3_BLOCK(dA4, uA4, BA4, CA4, tb);
        LOAD4S(dA4, uA4, BA4, CA4, tb + 32);   // final iter overreads (safe)
        P3_BLOCK(dB4, uB4, BB4, CB4, tb + 16);
    }
}

// Fused gate + transpose + bf16-split:
//   y = (s + D*u) * silu(z), emitted directly as row-major bf16 planes yh/yl.
// s read from the mapped xz x-half, u from uT, z from xz z-half (LDS tile).
__global__ __launch_bounds__(256) void gate_split_T(
    const float* __restrict__ xz, const float* __restrict__ uT,
    const float* __restrict__ Dskip,
    ushort_t* __restrict__ yh, ushort_t* __restrict__ yl)
{
    __shared__ float zt[64][65];   // [t][d]
    __shared__ float yt[64][65];   // [d][t]
    const int tid = threadIdx.x;
    const int d0 = blockIdx.x * 64, t0 = blockIdx.y * 64, b = blockIdx.z;
    const int cl = tid & 63, q = tid >> 6;
#pragma unroll
    for (int i = 0; i < 16; i++) {
        const int r = q * 16 + i;
        zt[r][cl] = xz[((size_t)b * SEQ + t0 + r) * (2 * DI) + DI + d0 + cl];
    }
    __syncthreads();
#pragma unroll
    for (int i = 0; i < 16; i++) {
        const int dd = q * 16 + i;
        const size_t Lrow = ((size_t)b * DI + d0 + dd) * SEQ + t0;
        const float s = xz[(Lrow / 1536) * 3072 + (Lrow % 1536) + cl];
        const float u = uT[Lrow + cl];
        const float Dd = Dskip[d0 + dd];   // wave-uniform
        yt[dd][cl] = (s + Dd * u) * silu_fast(zt[cl][dd]);
    }
    __syncthreads();
#pragma unroll
    for (int i = 0; i < 16; i++) {
        const int t = q * 16 + i;
        ushort_t h, l;
        bf16_split(yt[cl][t], h, l);
        const size_t row = (size_t)b * SEQ + t0 + t;
        yh[row * DI + d0 + cl] = h;        // coalesced in d
        yl[row * DI + d0 + cl] = l;
    }
}

extern "C" void kernel_launch(void* const* d_in, const int* in_sizes, int n_in,
                              void* d_out, int out_size, void* d_ws, size_t ws_size,
                              hipStream_t stream) {
    (void)in_sizes; (void)n_in; (void)out_size; (void)ws_size;
    const float* x    = (const float*)d_in[0];
    const float* Wi   = (const float*)d_in[1];
    const float* cw   = (const float*)d_in[2];
    const float* cb   = (const float*)d_in[3];
    const float* Wx   = (const float*)d_in[4];
    const float* Wdt  = (const float*)d_in[5];
    const float* bdt  = (const float*)d_in[6];
    const float* Alog = (const float*)d_in[7];
    const float* Dsk  = (const float*)d_in[8];
    const float* Wo   = (const float*)d_in[9];
    float* out = (float*)d_out;

    // Workspace (fp32) regions:
    float* xz    = (float*)d_ws;                          // [MROWS, 3072]: x-half xpart -> s(mapped); z-half z
    float* uT    = xz    + (size_t)MROWS * (2 * DI);      // sh/sl planes -> u fp32 -> sh/sl again (layer0 out)
    float* dtT   = uT    + (size_t)MROWS * DI;            // wih/wil -> uh/ul -> dt -> yl (upper half)
    float* xdbl  = dtT   + (size_t)MROWS * DI;            // x_proj C fp32; later woh/wol arena
    float* bcT   = xdbl  + (size_t)MROWS * XDC;           // wxh/wxl (padded) -> bc4 interleaved
    float* xnext = bcT   + (size_t)BATCH * 128 * SEQ;     // uh?no: hend/prodA -> yh
    float* hend  = xnext;                                 // [B*DI*NC, DS]
    float* prodA = xnext + (size_t)BATCH * DI * NC * DS;  // [B*DI*NC, DS]

    // bf16 plane homes (all lifetimes disjoint on the serial stream):
    ushort_t* sh  = (ushort_t*)uT;                        // [MROWS, DM] x2 (layer input planes)
    ushort_t* sl  = sh  + (size_t)MROWS * DM;
    ushort_t* wih = (ushort_t*)(dtT + (size_t)MROWS * DM);// [2*DI, DM] x2, dtT upper half
    ushort_t* wil = wih + (size_t)2 * DI * DM;
    ushort_t* uh  = (ushort_t*)dtT;                       // [MROWS, DI] x2 fills dtT region
    ushort_t* ul  = uh  + (size_t)MROWS * DI;
    ushort_t* wxh = (ushort_t*)bcT;                       // [256(pad), DI] x2 in bcT
    ushort_t* wxl = wxh + (size_t)256 * DI;
    ushort_t* woh = (ushort_t*)xdbl;                      // [DM, DI] x2
    ushort_t* wol = woh + (size_t)DM * DI;
    ushort_t* yh  = (ushort_t*)xnext;                     // [MROWS, DI]
    ushort_t* yl  = (ushort_t*)(dtT + (size_t)MROWS * DM);// [MROWS, DI], dtT upper half

    for (int i = 0; i < DEPTH; i++) {
        const float* Wi_l   = Wi   + (size_t)i * 2 * DI * DM;
        const float* cw_l   = cw   + (size_t)i * DI * DC;
        const float* cb_l   = cb   + (size_t)i * DI;
        const float* Wx_l   = Wx   + (size_t)i * XDC * DI;
        const float* Wdt_l  = Wdt  + (size_t)i * DI * DTR;
        const float* bdt_l  = bdt  + (size_t)i * DI;
        const float* Alog_l = Alog + (size_t)i * DI * DS;
        const float* Dsk_l  = Dsk  + (size_t)i * DI;
        const float* Wo_l   = Wo   + (size_t)i * DM * DI;

        // 1. input planes: layer 0 splits x; layer 1 already has sh/sl
        //    (emitted by layer 0's out-GEMM epilogue).
        if (i == 0)
            split_bf16<<<(size_t)MROWS * DM / 1024, 256, 0, stream>>>(x, sh, sl);
        split_bf16<<<(size_t)2 * DI * DM / 1024, 256, 0, stream>>>(Wi_l, wih, wil);
        // 2. xz = src @ Wi^T  (bf16x2 MFMA)        [8192, 3072]
        gemm_mfma<<<dim3(2 * DI / 128, MROWS / 128), 256, 0, stream>>>(
            sh, sl, wih, wil, xz, 2 * DI, DM, DM, DM, nullptr, nullptr);
        // 3. u = silu(conv(xz[:, :DI])) -> uT fp32 + uh/ul planes (dtT region)
        conv_silu_T2<<<dim3(DI / 64, SEQ / 64, BATCH), 256, 0, stream>>>(
            xz, cw_l, cb_l, uT, uh, ul);
        // 4. Wx planes (bcT region, 256-row padded; pad rows finite garbage)
        split_bf16<<<(size_t)XDC * DI / 1024, 256, 0, stream>>>(Wx_l, wxh, wxl);
        // 5. xdbl = u @ Wx^T  (bf16x2 MFMA, N=176 guarded)
        gemm_mfma<<<dim3((XDC + 127) / 128, MROWS / 128), 256, 0, stream>>>(
            uh, ul, wxh, wxl, xdbl, XDC, DI, DI, DI, nullptr, nullptr);
        // 6. B/C -> lane-interleaved bc4 layout (overwrites wxh/wxl, dead)
        trans_bc_i4<<<dim3(2, SEQ / 64, BATCH), 256, 0, stream>>>(
            xdbl, (float4*)bcT);
        // 7. dtT = softplus(Wdt @ xdbl_dt^T + bdt)  — direct transposed output
        gemm_dt_T<<<dim3(SEQ / 128, DI / 128, BATCH), 256, 0, stream>>>(
            Wdt_l, xdbl, bdt_l, dtT);
        // 8-10. chunked scan; phase3 writes s into xz x-half (mapped)
        scan_phase1<<<(BATCH * DI * NC) / 4, 256, 0, stream>>>(
            dtT, uT, (const float4*)bcT, Alog_l, hend, prodA);
        scan_phase2<<<(BATCH * DI) / 4, 256, 0, stream>>>(hend, prodA);
        scan_phase3<<<(BATCH * DI * NC) / 4, 256, 0, stream>>>(
            dtT, uT, (const float4*)bcT, Alog_l, prodA, xz);
        // 11. fused gate + split -> yh (xnext) / yl (dtT upper, dt dead)
        gate_split_T<<<dim3(DI / 64, SEQ / 64, BATCH), 256, 0, stream>>>(
            xz, uT, Dsk_l, yh, yl);
        // 12. Wo planes (xdbl region, dead)
        split_bf16<<<(size_t)DM * DI / 1024, 256, 0, stream>>>(Wo_l, woh, wol);
        // 13. out = y @ Wo^T  (bf16x2 MFMA); layer 0 emits planes sh/sl
        //     directly (consumed by layer 1's step 2), layer 1 emits fp32.
        if (i == DEPTH - 1)
            gemm_mfma<<<dim3(DM / 128, MROWS / 128), 256, 0, stream>>>(
                yh, yl, woh, wol, out, DM, DI, DI, DI, nullptr, nullptr);
        else
            gemm_mfma<<<dim3(DM / 128, MROWS / 128), 256, 0, stream>>>(
                yh, yl, woh, wol, xz /*unused*/, DM, DI, DI, DI, sh, sl);
    }
}